// Round 1
// baseline (1830.189 us; speedup 1.0000x reference)
//
#include <hip/hip_runtime.h>

typedef unsigned long long u64;

// ---------------------------------------------------------------------------
// HierarchicalLFQHVQVAE forward, f32 reference-accurate implementation.
// R1 plan: correctness anchor. All GEMMs f32 VALU (no fp32 MFMA on CDNA4).
// Quantize = fused GEMM + per-row argmin via packed (dist,idx) u64 atomicMin
// (tie -> lowest index, matching jnp.argmin first-occurrence).
// ---------------------------------------------------------------------------

namespace {

constexpr int kBatch = 32768;

__device__ __forceinline__ float gelu_f(float x) {
  // exact (erf) GELU, matches jax.nn.gelu(approximate=False)
  return 0.5f * x * (1.0f + erff(x * 0.70710678118654752440f));
}
__device__ __forceinline__ float sigmoid_f(float x) {
  return 1.0f / (1.0f + expf(-x));
}
__device__ __forceinline__ u64 pack_key(float d, unsigned j) {
  // monotone float->u32 map; key min == (dist, idx) lexicographic min
  unsigned u = __float_as_uint(d);
  u = (u & 0x80000000u) ? ~u : (u | 0x80000000u);
  return ((u64)u << 32) | j;
}

// --- Lipschitz row normalization: Wn[n,:] = W[n,:] * min(1, softplus(ci)/L1)
__global__ void norm_rows_kernel(const float* __restrict__ W,
                                 const float* __restrict__ ci,
                                 float* __restrict__ Wn, int K) {
  const int row = blockIdx.x;
  const int tid = threadIdx.x;
  float s = 0.f;
  for (int k = tid; k < K; k += 256) s += fabsf(W[(size_t)row * K + k]);
#pragma unroll
  for (int o = 32; o > 0; o >>= 1) s += __shfl_down(s, o);
  __shared__ float p[4];
  if ((tid & 63) == 0) p[tid >> 6] = s;
  __syncthreads();
  const float tot = p[0] + p[1] + p[2] + p[3];
  const float c = ci[row];
  const float sp = (c > 20.f) ? c : log1pf(expf(c));
  const float scale = fminf(1.f, sp / tot);
  for (int k = tid; k < K; k += 256)
    Wn[(size_t)row * K + k] = W[(size_t)row * K + k] * scale;
}

// --- codebook squared norms (f64 accumulate: keeps dist error ~1e-5)
__global__ void cb_norm_kernel(const float* __restrict__ cb,
                               float* __restrict__ cbn, int K) {
  const int row = blockIdx.x * 4 + (threadIdx.x >> 6);
  const int lane = threadIdx.x & 63;
  double s = 0.0;
  for (int k = lane; k < K; k += 64) {
    const float v = cb[(size_t)row * K + k];
    s += (double)v * (double)v;
  }
#pragma unroll
  for (int o = 32; o > 0; o >>= 1) s += __shfl_down(s, o);
  if (lane == 0) cbn[row] = (float)s;
}

// ---------------------------------------------------------------------------
// Big tiled GEMM: C[B,N] = epilogue(A[B,K] @ W[N,K]^T).
// 128x128 block tile, TK=16, 256 threads, 8x8 per thread (2x2 blocks of 4x4 at
// stride-64). LDS halves at col offsets {0, 68} (stride 136) -> every LDS
// read/write pattern is <=2-way bank aliasing (free on CDNA4, m136).
// Modes: 0=GELU+bias  1=sigmoid+bias  2=bias+store(float2)+sum((c-x)^2)
//        3=dist: per-row argmin of (cbn[j] - 2*dot) -> atomicMin(u64)
// ---------------------------------------------------------------------------
enum { MODE_GELU = 0, MODE_SIGMOID = 1, MODE_RECON = 2, MODE_DIST = 3 };

template <int MODE>
__global__ __launch_bounds__(256, 3) void gemm_big(
    const float* __restrict__ A, const float* __restrict__ W,
    const float* __restrict__ bias, float* __restrict__ C,
    const float* __restrict__ X, float* __restrict__ sumptr,
    u64* __restrict__ minkey, int K, int N) {
  __shared__ __align__(16) float As[16][136];
  __shared__ __align__(16) float Ws[16][136];
  const int tid = threadIdx.x;
  const int tx = tid & 15, ty = tid >> 4;
  const int rowBase = blockIdx.y * 128;
  const int colBase = blockIdx.x * 128;
  const int lrow = tid >> 1;              // 0..127
  const int lk = (tid & 1) * 8;           // 0 or 8
  const int pr = (lrow < 64) ? lrow : lrow + 4;  // physical LDS col (halves)

  float acc[2][2][4][4] = {};

  const float* Aptr = A + (size_t)(rowBase + lrow) * K + lk;
  const float* Wptr = W + (size_t)(colBase + lrow) * K + lk;

  for (int k0 = 0; k0 < K; k0 += 16) {
    const float4 a0 = *(const float4*)(Aptr + k0);
    const float4 a1 = *(const float4*)(Aptr + k0 + 4);
    const float4 w0 = *(const float4*)(Wptr + k0);
    const float4 w1 = *(const float4*)(Wptr + k0 + 4);
    __syncthreads();
    As[lk + 0][pr] = a0.x; As[lk + 1][pr] = a0.y;
    As[lk + 2][pr] = a0.z; As[lk + 3][pr] = a0.w;
    As[lk + 4][pr] = a1.x; As[lk + 5][pr] = a1.y;
    As[lk + 6][pr] = a1.z; As[lk + 7][pr] = a1.w;
    Ws[lk + 0][pr] = w0.x; Ws[lk + 1][pr] = w0.y;
    Ws[lk + 2][pr] = w0.z; Ws[lk + 3][pr] = w0.w;
    Ws[lk + 4][pr] = w1.x; Ws[lk + 5][pr] = w1.y;
    Ws[lk + 6][pr] = w1.z; Ws[lk + 7][pr] = w1.w;
    __syncthreads();
#pragma unroll
    for (int kk = 0; kk < 16; ++kk) {
      const float4 av0 = *(const float4*)&As[kk][4 * ty];
      const float4 av1 = *(const float4*)&As[kk][68 + 4 * ty];
      const float4 wv0 = *(const float4*)&Ws[kk][4 * tx];
      const float4 wv1 = *(const float4*)&Ws[kk][68 + 4 * tx];
      const float ar[2][4] = {{av0.x, av0.y, av0.z, av0.w},
                              {av1.x, av1.y, av1.z, av1.w}};
      const float wr[2][4] = {{wv0.x, wv0.y, wv0.z, wv0.w},
                              {wv1.x, wv1.y, wv1.z, wv1.w}};
#pragma unroll
      for (int ih = 0; ih < 2; ++ih)
#pragma unroll
        for (int i = 0; i < 4; ++i)
#pragma unroll
          for (int jh = 0; jh < 2; ++jh)
#pragma unroll
            for (int j = 0; j < 4; ++j)
              acc[ih][jh][i][j] =
                  fmaf(ar[ih][i], wr[jh][j], acc[ih][jh][i][j]);
    }
  }

  if constexpr (MODE == MODE_GELU || MODE == MODE_SIGMOID) {
#pragma unroll
    for (int ih = 0; ih < 2; ++ih)
#pragma unroll
      for (int i = 0; i < 4; ++i) {
        const int r = rowBase + 64 * ih + 4 * ty + i;
#pragma unroll
        for (int jh = 0; jh < 2; ++jh) {
          const int c0 = colBase + 64 * jh + 4 * tx;
          float4 v;
          float* vp = &v.x;
#pragma unroll
          for (int j = 0; j < 4; ++j) {
            float val = acc[ih][jh][i][j] + bias[c0 + j];
            vp[j] = (MODE == MODE_GELU) ? gelu_f(val) : sigmoid_f(val);
          }
          *(float4*)(C + (size_t)r * N + c0) = v;
        }
      }
  } else if constexpr (MODE == MODE_RECON) {
    float localsum = 0.f;
#pragma unroll
    for (int ih = 0; ih < 2; ++ih)
#pragma unroll
      for (int i = 0; i < 4; ++i) {
        const int r = rowBase + 64 * ih + 4 * ty + i;
#pragma unroll
        for (int jh = 0; jh < 2; ++jh) {
          const int c0 = colBase + 64 * jh + 4 * tx;
          float vv[4];
#pragma unroll
          for (int j = 0; j < 4; ++j) {
            const float val = acc[ih][jh][i][j] + bias[c0 + j];
            const float d = val - X[(size_t)r * N + c0 + j];
            localsum += d * d;
            vv[j] = val;
          }
          // d_out region is only 8-byte aligned (offset 6 floats) -> float2
          *(float2*)(C + (size_t)r * N + c0) = make_float2(vv[0], vv[1]);
          *(float2*)(C + (size_t)r * N + c0 + 2) = make_float2(vv[2], vv[3]);
        }
      }
#pragma unroll
    for (int o = 32; o > 0; o >>= 1) localsum += __shfl_down(localsum, o);
    __shared__ float psum[4];
    if ((tid & 63) == 0) psum[tid >> 6] = localsum;
    __syncthreads();
    if (tid == 0) atomicAdd(sumptr, psum[0] + psum[1] + psum[2] + psum[3]);
  } else {  // MODE_DIST
    __shared__ u64 red[128][17];
#pragma unroll
    for (int ih = 0; ih < 2; ++ih)
#pragma unroll
      for (int i = 0; i < 4; ++i) {
        const int rloc = 64 * ih + 4 * ty + i;
        u64 best = 0xFFFFFFFFFFFFFFFFULL;
#pragma unroll
        for (int jh = 0; jh < 2; ++jh)
#pragma unroll
          for (int j = 0; j < 4; ++j) {
            const int c = colBase + 64 * jh + 4 * tx + j;
            const float dist = bias[c] - 2.0f * acc[ih][jh][i][j];
            const u64 k = pack_key(dist, (unsigned)c);
            best = (k < best) ? k : best;
          }
        red[rloc][tx] = best;
      }
    __syncthreads();
    if (tid < 128) {
      u64 b = red[tid][0];
#pragma unroll
      for (int t = 1; t < 16; ++t) {
        const u64 v = red[tid][t];
        b = (v < b) ? v : b;
      }
      atomicMin(&minkey[rowBase + tid], b);
    }
  }
}

// --- small GEMM for the two N=64 GELU layers (64x64 tile, 4x4/thread) ------
__global__ __launch_bounds__(256, 4) void gemm_small_gelu(
    const float* __restrict__ A, const float* __restrict__ W,
    const float* __restrict__ bias, float* __restrict__ C, int K, int N) {
  __shared__ __align__(16) float As[16][68];
  __shared__ __align__(16) float Ws[16][68];
  const int tid = threadIdx.x;
  const int tx = tid & 15, ty = tid >> 4;
  const int rowBase = blockIdx.y * 64;
  const int colBase = blockIdx.x * 64;
  const int lrow = tid >> 2;         // 0..63
  const int lk = (tid & 3) * 4;      // 0,4,8,12
  float acc[4][4] = {};
  const float* Aptr = A + (size_t)(rowBase + lrow) * K + lk;
  const float* Wptr = W + (size_t)(colBase + lrow) * K + lk;
  for (int k0 = 0; k0 < K; k0 += 16) {
    const float4 a = *(const float4*)(Aptr + k0);
    const float4 w = *(const float4*)(Wptr + k0);
    __syncthreads();
    As[lk + 0][lrow] = a.x; As[lk + 1][lrow] = a.y;
    As[lk + 2][lrow] = a.z; As[lk + 3][lrow] = a.w;
    Ws[lk + 0][lrow] = w.x; Ws[lk + 1][lrow] = w.y;
    Ws[lk + 2][lrow] = w.z; Ws[lk + 3][lrow] = w.w;
    __syncthreads();
#pragma unroll
    for (int kk = 0; kk < 16; ++kk) {
      const float4 av = *(const float4*)&As[kk][4 * ty];
      const float4 wv = *(const float4*)&Ws[kk][4 * tx];
      const float ar[4] = {av.x, av.y, av.z, av.w};
      const float wr[4] = {wv.x, wv.y, wv.z, wv.w};
#pragma unroll
      for (int i = 0; i < 4; ++i)
#pragma unroll
        for (int j = 0; j < 4; ++j)
          acc[i][j] = fmaf(ar[i], wr[j], acc[i][j]);
    }
  }
#pragma unroll
  for (int i = 0; i < 4; ++i) {
    const int r = rowBase + 4 * ty + i;
    const int c0 = colBase + 4 * tx;
    float4 v;
    float* vp = &v.x;
#pragma unroll
    for (int j = 0; j < 4; ++j) vp[j] = gelu_f(acc[i][j] + bias[c0 + j]);
    *(float4*)(C + (size_t)r * N + c0) = v;
  }
}

// --- gather chosen code, write z_q (out + aligned ws in-place), idx, commit
__global__ void gather_commit_kernel(float* __restrict__ zeq,  // in: z_e, out: z_q
                                     const float* __restrict__ cb,
                                     const u64* __restrict__ mk,
                                     float* out_q, float* out_idx,
                                     float* sumptr, int cols) {
  const int w = threadIdx.x >> 6, lane = threadIdx.x & 63;
  const int row = blockIdx.x * 4 + w;
  const u64 key = mk[row];
  const int idx = (int)(unsigned)(key & 0xFFFFFFFFULL);
  if (lane == 0) out_idx[row] = (float)idx;
  float local = 0.f;
  for (int c = lane; c < cols; c += 64) {
    const float ze = zeq[(size_t)row * cols + c];   // read BEFORE overwrite
    const float v = cb[(size_t)idx * cols + c];
    zeq[(size_t)row * cols + c] = v;                // aligned copy for next GEMM
    out_q[(size_t)row * cols + c] = v;
    const float d = ze - v;
    local += d * d;
  }
#pragma unroll
  for (int o = 32; o > 0; o >>= 1) local += __shfl_down(local, o);
  __shared__ float p[4];
  if (lane == 0) p[w] = local;
  __syncthreads();
  if (threadIdx.x == 0) atomicAdd(sumptr, p[0] + p[1] + p[2] + p[3]);
}

__global__ void finalize_kernel(const float* __restrict__ sums,
                                float* __restrict__ out) {
  const float cz = sums[0] / ((float)kBatch * 256.f);
  const float cq = sums[1] / ((float)kBatch * 128.f);
  const float rec = sums[2] / ((float)kBatch * 512.f);
  out[0] = rec + 0.5f * cz + 0.5f * cq;  // 0.25*(cz+cz) + 0.25*(cq+cq)
  out[1] = rec;
  out[2] = cz;
  out[3] = cz;
  out[4] = cq;
  out[5] = cq;
}

}  // namespace

extern "C" void kernel_launch(void* const* d_in, const int* in_sizes, int n_in,
                              void* d_out, int out_size, void* d_ws,
                              size_t ws_size, hipStream_t stream) {
  const float* x   = (const float*)d_in[0];
  const float* eW1 = (const float*)d_in[1];
  const float* eb1 = (const float*)d_in[2];
  const float* eW2 = (const float*)d_in[3];
  const float* eb2 = (const float*)d_in[4];
  const float* zW  = (const float*)d_in[5];
  const float* zb  = (const float*)d_in[6];
  const float* zci = (const float*)d_in[7];
  const float* zcb = (const float*)d_in[8];
  const float* qW  = (const float*)d_in[9];
  const float* qb  = (const float*)d_in[10];
  const float* qci = (const float*)d_in[11];
  const float* qcb = (const float*)d_in[12];
  const float* dW1 = (const float*)d_in[13];
  const float* db1 = (const float*)d_in[14];
  const float* dW2 = (const float*)d_in[15];
  const float* db2 = (const float*)d_in[16];
  const float* oW  = (const float*)d_in[17];
  const float* ob  = (const float*)d_in[18];

  float* out = (float*)d_out;
  float* out_xr = out + 6;
  float* out_zq = out_xr + (size_t)32768 * 512;
  float* out_qq = out_zq + (size_t)32768 * 256;
  float* out_zi = out_qq + (size_t)32768 * 128;
  float* out_qi = out_zi + 32768;

  // workspace layout (all 16B-aligned; ~128 MB)
  char* wsb = (char*)d_ws;
  float* zWn  = (float*)(wsb + 0x0000000);  // 512 KB
  float* qWn  = (float*)(wsb + 0x0080000);  // 128 KB
  float* zcbn = (float*)(wsb + 0x00A0000);  // 16 KB
  float* qcbn = (float*)(wsb + 0x00A4000);  // 8 KB
  float* sums = (float*)(wsb + 0x00A6000);  // 3 floats {commit_z, commit_q, recon}
  u64*  mkz   = (u64*) (wsb + 0x00A8000);   // 256 KB
  u64*  mkq   = (u64*) (wsb + 0x00E8000);   // 256 KB
  float* h1   = (float*)(wsb + 0x0200000);  // 8 MB  (also decoder hidden1)
  float* h    = (float*)(wsb + 0x0A00000);  // 64 MB (also decoder hidden2)
  float* ze   = (float*)(wsb + 0x4A00000);  // 32 MB (z_e, then z_q in-place)
  float* qe   = (float*)(wsb + 0x6A00000);  // 16 MB (q_e, then q_q in-place)

  hipMemsetAsync(mkz, 0xFF, (size_t)32768 * 8, stream);
  hipMemsetAsync(mkq, 0xFF, (size_t)32768 * 8, stream);
  hipMemsetAsync(sums, 0, 3 * sizeof(float), stream);

  // weight prep
  norm_rows_kernel<<<256, 256, 0, stream>>>(zW, zci, zWn, 512);
  norm_rows_kernel<<<128, 256, 0, stream>>>(qW, qci, qWn, 256);
  cb_norm_kernel<<<1024, 256, 0, stream>>>(zcb, zcbn, 256);
  cb_norm_kernel<<<512, 256, 0, stream>>>(qcb, qcbn, 128);

  // encoder
  gemm_small_gelu<<<dim3(1, 512), 256, 0, stream>>>(x, eW1, eb1, h1, 512, 64);
  gemm_big<MODE_GELU><<<dim3(4, 256), 256, 0, stream>>>(
      h1, eW2, eb2, h, nullptr, nullptr, nullptr, 64, 512);
  gemm_big<MODE_SIGMOID><<<dim3(2, 256), 256, 0, stream>>>(
      h, zWn, zb, ze, nullptr, nullptr, nullptr, 512, 256);

  // z quantize
  gemm_big<MODE_DIST><<<dim3(32, 256), 256, 0, stream>>>(
      ze, zcb, zcbn, nullptr, nullptr, nullptr, mkz, 256, 4096);
  gather_commit_kernel<<<8192, 256, 0, stream>>>(ze, zcb, mkz, out_zq, out_zi,
                                                 &sums[0], 256);

  // q level (ze now holds z_q)
  gemm_big<MODE_SIGMOID><<<dim3(1, 256), 256, 0, stream>>>(
      ze, qWn, qb, qe, nullptr, nullptr, nullptr, 256, 128);
  gemm_big<MODE_DIST><<<dim3(16, 256), 256, 0, stream>>>(
      qe, qcb, qcbn, nullptr, nullptr, nullptr, mkq, 128, 2048);
  gather_commit_kernel<<<8192, 256, 0, stream>>>(qe, qcb, mkq, out_qq, out_qi,
                                                 &sums[1], 128);

  // decoder (qe now holds q_q)
  gemm_small_gelu<<<dim3(1, 512), 256, 0, stream>>>(qe, dW1, db1, h1, 128, 64);
  gemm_big<MODE_GELU><<<dim3(4, 256), 256, 0, stream>>>(
      h1, dW2, db2, h, nullptr, nullptr, nullptr, 64, 512);
  gemm_big<MODE_RECON><<<dim3(4, 256), 256, 0, stream>>>(
      h, oW, ob, out_xr, x, &sums[2], nullptr, 512, 512);

  finalize_kernel<<<1, 1, 0, stream>>>(sums, out);

  (void)in_sizes; (void)n_in; (void)out_size; (void)ws_size;
}

// Round 2
// 1249.227 us; speedup vs baseline: 1.4651x; 1.4651x over previous
//
#include <hip/hip_runtime.h>

typedef unsigned long long u64;

// ---------------------------------------------------------------------------
// HierarchicalLFQHVQVAE forward.
// R2: distance GEMMs (z: 32768x4096xK256, q: 32768x2048xK128) moved to bf16
// MFMA using 2-way-split emulation concatenated along K (K' = 3K):
//   A' = [ah | al | ah],  B' = [bh | bh | bl],  dot ~= ah.bh + al.bh + ah.bl
// (missing al.bl term ~2^-18 |ab| -> distance error ~5e-5 == f32-level).
// Everything else stays f32 VALU from R1 (correct, to be converted later).
// ---------------------------------------------------------------------------

namespace {

constexpr int kBatch = 32768;

__device__ __forceinline__ float gelu_f(float x) {
  return 0.5f * x * (1.0f + erff(x * 0.70710678118654752440f));
}
__device__ __forceinline__ float sigmoid_f(float x) {
  return 1.0f / (1.0f + expf(-x));
}
__device__ __forceinline__ u64 pack_key(float d, unsigned j) {
  unsigned u = __float_as_uint(d);
  u = (u & 0x80000000u) ? ~u : (u | 0x80000000u);
  return ((u64)u << 32) | j;
}
__device__ __forceinline__ unsigned short bf16_rne(float x) {
  unsigned u = __float_as_uint(x);
  unsigned r = (u + 0x7FFFu + ((u >> 16) & 1u)) >> 16;
  return (unsigned short)r;
}
__device__ __forceinline__ float bf16_to_f(unsigned short h) {
  return __uint_as_float((unsigned)h << 16);
}

__device__ __forceinline__ void load_lds16(const void* g, void* l) {
  __builtin_amdgcn_global_load_lds(
      (const __attribute__((address_space(1))) void*)g,
      (__attribute__((address_space(3))) void*)l, 16, 0, 0);
}

typedef short bf16x8 __attribute__((ext_vector_type(8)));
typedef float f32x4 __attribute__((ext_vector_type(4)));

// --- Lipschitz row normalization -------------------------------------------
__global__ void norm_rows_kernel(const float* __restrict__ W,
                                 const float* __restrict__ ci,
                                 float* __restrict__ Wn, int K) {
  const int row = blockIdx.x;
  const int tid = threadIdx.x;
  float s = 0.f;
  for (int k = tid; k < K; k += 256) s += fabsf(W[(size_t)row * K + k]);
#pragma unroll
  for (int o = 32; o > 0; o >>= 1) s += __shfl_down(s, o);
  __shared__ float p[4];
  if ((tid & 63) == 0) p[tid >> 6] = s;
  __syncthreads();
  const float tot = p[0] + p[1] + p[2] + p[3];
  const float c = ci[row];
  const float sp = (c > 20.f) ? c : log1pf(expf(c));
  const float scale = fminf(1.f, sp / tot);
  for (int k = tid; k < K; k += 256)
    Wn[(size_t)row * K + k] = W[(size_t)row * K + k] * scale;
}

// --- codebook squared norms (f64 accumulate) -------------------------------
__global__ void cb_norm_kernel(const float* __restrict__ cb,
                               float* __restrict__ cbn, int K) {
  const int row = blockIdx.x * 4 + (threadIdx.x >> 6);
  const int lane = threadIdx.x & 63;
  double s = 0.0;
  for (int k = lane; k < K; k += 64) {
    const float v = cb[(size_t)row * K + k];
    s += (double)v * (double)v;
  }
#pragma unroll
  for (int o = 32; o > 0; o >>= 1) s += __shfl_down(s, o);
  if (lane == 0) cbn[row] = (float)s;
}

// --- codebook split prep: row -> [bh(K) | bh(K) | bl(K)] bf16 --------------
__global__ void split_cb_kernel(const float* __restrict__ cb,
                                unsigned short* __restrict__ S, int K,
                                int kshift, int total) {
  const int i = blockIdx.x * 256 + threadIdx.x;
  if (i >= total) return;
  const int n = i >> kshift;
  const int k = i & (K - 1);
  const float v = cb[i];
  const unsigned short hi = bf16_rne(v);
  const unsigned short lo = bf16_rne(v - bf16_to_f(hi));
  unsigned short* row = S + (size_t)n * 3 * K;
  row[k] = hi;
  row[K + k] = hi;
  row[2 * K + k] = lo;
}

// ---------------------------------------------------------------------------
// f32 tiled GEMM: 128x128 tile, 8x8/thread. Modes:
//  GELU: C = gelu(A@W^T + b) f32
//  SIGMOID: writes split-bf16 [ah|al|ah] rows (stride 3N) of sigmoid output
//  RECON: C = A@W^T + b (float2 stores) + atomicAdd sum((C - X)^2)
// ---------------------------------------------------------------------------
enum { MODE_GELU = 0, MODE_SIGMOID = 1, MODE_RECON = 2 };

template <int MODE>
__global__ __launch_bounds__(256, 3) void gemm_big(
    const float* __restrict__ A, const float* __restrict__ W,
    const float* __restrict__ bias, float* __restrict__ C,
    const float* __restrict__ X, float* __restrict__ sumptr, int K, int N) {
  __shared__ __align__(16) float As[16][136];
  __shared__ __align__(16) float Ws[16][136];
  const int tid = threadIdx.x;
  const int tx = tid & 15, ty = tid >> 4;
  const int rowBase = blockIdx.y * 128;
  const int colBase = blockIdx.x * 128;
  const int lrow = tid >> 1;
  const int lk = (tid & 1) * 8;
  const int pr = (lrow < 64) ? lrow : lrow + 4;

  float acc[2][2][4][4] = {};

  const float* Aptr = A + (size_t)(rowBase + lrow) * K + lk;
  const float* Wptr = W + (size_t)(colBase + lrow) * K + lk;

  for (int k0 = 0; k0 < K; k0 += 16) {
    const float4 a0 = *(const float4*)(Aptr + k0);
    const float4 a1 = *(const float4*)(Aptr + k0 + 4);
    const float4 w0 = *(const float4*)(Wptr + k0);
    const float4 w1 = *(const float4*)(Wptr + k0 + 4);
    __syncthreads();
    As[lk + 0][pr] = a0.x; As[lk + 1][pr] = a0.y;
    As[lk + 2][pr] = a0.z; As[lk + 3][pr] = a0.w;
    As[lk + 4][pr] = a1.x; As[lk + 5][pr] = a1.y;
    As[lk + 6][pr] = a1.z; As[lk + 7][pr] = a1.w;
    Ws[lk + 0][pr] = w0.x; Ws[lk + 1][pr] = w0.y;
    Ws[lk + 2][pr] = w0.z; Ws[lk + 3][pr] = w0.w;
    Ws[lk + 4][pr] = w1.x; Ws[lk + 5][pr] = w1.y;
    Ws[lk + 6][pr] = w1.z; Ws[lk + 7][pr] = w1.w;
    __syncthreads();
#pragma unroll
    for (int kk = 0; kk < 16; ++kk) {
      const float4 av0 = *(const float4*)&As[kk][4 * ty];
      const float4 av1 = *(const float4*)&As[kk][68 + 4 * ty];
      const float4 wv0 = *(const float4*)&Ws[kk][4 * tx];
      const float4 wv1 = *(const float4*)&Ws[kk][68 + 4 * tx];
      const float ar[2][4] = {{av0.x, av0.y, av0.z, av0.w},
                              {av1.x, av1.y, av1.z, av1.w}};
      const float wr[2][4] = {{wv0.x, wv0.y, wv0.z, wv0.w},
                              {wv1.x, wv1.y, wv1.z, wv1.w}};
#pragma unroll
      for (int ih = 0; ih < 2; ++ih)
#pragma unroll
        for (int i = 0; i < 4; ++i)
#pragma unroll
          for (int jh = 0; jh < 2; ++jh)
#pragma unroll
            for (int j = 0; j < 4; ++j)
              acc[ih][jh][i][j] =
                  fmaf(ar[ih][i], wr[jh][j], acc[ih][jh][i][j]);
    }
  }

  if constexpr (MODE == MODE_GELU) {
#pragma unroll
    for (int ih = 0; ih < 2; ++ih)
#pragma unroll
      for (int i = 0; i < 4; ++i) {
        const int r = rowBase + 64 * ih + 4 * ty + i;
#pragma unroll
        for (int jh = 0; jh < 2; ++jh) {
          const int c0 = colBase + 64 * jh + 4 * tx;
          float4 v;
          float* vp = &v.x;
#pragma unroll
          for (int j = 0; j < 4; ++j)
            vp[j] = gelu_f(acc[ih][jh][i][j] + bias[c0 + j]);
          *(float4*)(C + (size_t)r * N + c0) = v;
        }
      }
  } else if constexpr (MODE == MODE_SIGMOID) {
    unsigned short* S = (unsigned short*)C;
    const int stride = 3 * N;
#pragma unroll
    for (int ih = 0; ih < 2; ++ih)
#pragma unroll
      for (int i = 0; i < 4; ++i) {
        const int r = rowBase + 64 * ih + 4 * ty + i;
#pragma unroll
        for (int jh = 0; jh < 2; ++jh) {
          const int c0 = colBase + 64 * jh + 4 * tx;
          unsigned short h16[4], l16[4];
#pragma unroll
          for (int j = 0; j < 4; ++j) {
            const float s = sigmoid_f(acc[ih][jh][i][j] + bias[c0 + j]);
            h16[j] = bf16_rne(s);
            l16[j] = bf16_rne(s - bf16_to_f(h16[j]));
          }
          const ushort4 hv = make_ushort4(h16[0], h16[1], h16[2], h16[3]);
          const ushort4 lv = make_ushort4(l16[0], l16[1], l16[2], l16[3]);
          unsigned short* rowp = S + (size_t)r * stride + c0;
          *(ushort4*)(rowp) = hv;
          *(ushort4*)(rowp + N) = lv;
          *(ushort4*)(rowp + 2 * N) = hv;
        }
      }
  } else {  // MODE_RECON
    float localsum = 0.f;
#pragma unroll
    for (int ih = 0; ih < 2; ++ih)
#pragma unroll
      for (int i = 0; i < 4; ++i) {
        const int r = rowBase + 64 * ih + 4 * ty + i;
#pragma unroll
        for (int jh = 0; jh < 2; ++jh) {
          const int c0 = colBase + 64 * jh + 4 * tx;
          float vv[4];
#pragma unroll
          for (int j = 0; j < 4; ++j) {
            const float val = acc[ih][jh][i][j] + bias[c0 + j];
            const float d = val - X[(size_t)r * N + c0 + j];
            localsum += d * d;
            vv[j] = val;
          }
          *(float2*)(C + (size_t)r * N + c0) = make_float2(vv[0], vv[1]);
          *(float2*)(C + (size_t)r * N + c0 + 2) = make_float2(vv[2], vv[3]);
        }
      }
#pragma unroll
    for (int o = 32; o > 0; o >>= 1) localsum += __shfl_down(localsum, o);
    __shared__ float psum[4];
    if ((tid & 63) == 0) psum[tid >> 6] = localsum;
    __syncthreads();
    if (tid == 0) atomicAdd(sumptr, psum[0] + psum[1] + psum[2] + psum[3]);
  }
}

// ---------------------------------------------------------------------------
// MFMA bf16 distance kernel. A [M][Ktot], B [N][Ktot] split-bf16 row-major.
// 128x128 tile, BK=64, 4 waves, each 64x64 = 4x4 MFMA 16x16x32 tiles.
// Staging via global_load_lds(16B) with XOR chunk swizzle so fragment
// ds_read_b128s are 2-way-aliased (free). Epilogue: dist = cbn[j] - 2*acc,
// packed-key min reduce -> 128 global atomicMin per block.
// ---------------------------------------------------------------------------
__global__ __launch_bounds__(256) void dist_mfma(
    const unsigned short* __restrict__ A, const unsigned short* __restrict__ B,
    const float* __restrict__ cbn, u64* __restrict__ minkey, int Ktot) {
  __shared__ __align__(16) unsigned short Asmem[128 * 64];
  __shared__ __align__(16) unsigned short Bsmem[128 * 64];
  __shared__ u64 red[128];
  const int tid = threadIdx.x;
  const int lane = tid & 63;
  const int w = tid >> 6;
  const int quad = lane >> 4;
  const int l15 = lane & 15;
  const int waveM = (w & 1) * 64, waveN = (w >> 1) * 64;
  const int rowBase = blockIdx.y * 128;
  const int colBase = blockIdx.x * 128;

  f32x4 acc[4][4] = {};

  for (int k0 = 0; k0 < Ktot; k0 += 64) {
    __syncthreads();
#pragma unroll
    for (int is = 0; is < 4; ++is) {
      const int chunk = is * 256 + tid;  // 0..1023 = (row 0..127) x (8 chunks)
      const int r = chunk >> 3, c = chunk & 7;
      const int g = c ^ (r & 7);  // swizzled source chunk
      load_lds16(A + (size_t)(rowBase + r) * Ktot + k0 + g * 8,
                 (char*)Asmem + chunk * 16);
      load_lds16(B + (size_t)(colBase + r) * Ktot + k0 + g * 8,
                 (char*)Bsmem + chunk * 16);
    }
    __syncthreads();
#pragma unroll
    for (int ks = 0; ks < 2; ++ks) {
      bf16x8 af[4], bf[4];
      const int ch = ks * 4 + quad;
#pragma unroll
      for (int mi = 0; mi < 4; ++mi) {
        const int rl = waveM + mi * 16 + l15;
        const int sw = ch ^ (rl & 7);
        af[mi] = *(const bf16x8*)(Asmem + rl * 64 + sw * 8);
      }
#pragma unroll
      for (int ni = 0; ni < 4; ++ni) {
        const int rl = waveN + ni * 16 + l15;
        const int sw = ch ^ (rl & 7);
        bf[ni] = *(const bf16x8*)(Bsmem + rl * 64 + sw * 8);
      }
#pragma unroll
      for (int mi = 0; mi < 4; ++mi)
#pragma unroll
        for (int ni = 0; ni < 4; ++ni)
          acc[mi][ni] = __builtin_amdgcn_mfma_f32_16x16x32_bf16(
              af[mi], bf[ni], acc[mi][ni], 0, 0, 0);
    }
  }

  // epilogue: per-row argmin of dist = cbn[col] - 2*acc
  float cn[4];
#pragma unroll
  for (int ni = 0; ni < 4; ++ni)
    cn[ni] = cbn[colBase + waveN + ni * 16 + l15];

  for (int i = tid; i < 128; i += 256) red[i] = ~0ull;
  __syncthreads();
#pragma unroll
  for (int mi = 0; mi < 4; ++mi) {
#pragma unroll
    for (int r = 0; r < 4; ++r) {
      u64 best = ~0ull;
#pragma unroll
      for (int ni = 0; ni < 4; ++ni) {
        const unsigned col = colBase + waveN + ni * 16 + l15;
        const float dist = cn[ni] - 2.0f * acc[mi][ni][r];
        const u64 key = pack_key(dist, col);
        best = (key < best) ? key : best;
      }
#pragma unroll
      for (int off = 1; off < 16; off <<= 1) {
        const u64 o = __shfl_xor(best, off);
        best = (o < best) ? o : best;
      }
      if (l15 == 0)
        atomicMin(&red[waveM + mi * 16 + quad * 4 + r], best);
    }
  }
  __syncthreads();
  if (tid < 128) {
    const u64 b = red[tid];
    atomicMin(&minkey[rowBase + tid], b);
  }
}

// --- small GEMM (N=64 GELU layers) -----------------------------------------
__global__ __launch_bounds__(256, 4) void gemm_small_gelu(
    const float* __restrict__ A, const float* __restrict__ W,
    const float* __restrict__ bias, float* __restrict__ C, int K, int N) {
  __shared__ __align__(16) float As[16][68];
  __shared__ __align__(16) float Ws[16][68];
  const int tid = threadIdx.x;
  const int tx = tid & 15, ty = tid >> 4;
  const int rowBase = blockIdx.y * 64;
  const int colBase = blockIdx.x * 64;
  const int lrow = tid >> 2;
  const int lk = (tid & 3) * 4;
  float acc[4][4] = {};
  const float* Aptr = A + (size_t)(rowBase + lrow) * K + lk;
  const float* Wptr = W + (size_t)(colBase + lrow) * K + lk;
  for (int k0 = 0; k0 < K; k0 += 16) {
    const float4 a = *(const float4*)(Aptr + k0);
    const float4 wv = *(const float4*)(Wptr + k0);
    __syncthreads();
    As[lk + 0][lrow] = a.x; As[lk + 1][lrow] = a.y;
    As[lk + 2][lrow] = a.z; As[lk + 3][lrow] = a.w;
    Ws[lk + 0][lrow] = wv.x; Ws[lk + 1][lrow] = wv.y;
    Ws[lk + 2][lrow] = wv.z; Ws[lk + 3][lrow] = wv.w;
    __syncthreads();
#pragma unroll
    for (int kk = 0; kk < 16; ++kk) {
      const float4 av = *(const float4*)&As[kk][4 * ty];
      const float4 wr4 = *(const float4*)&Ws[kk][4 * tx];
      const float ar[4] = {av.x, av.y, av.z, av.w};
      const float wr[4] = {wr4.x, wr4.y, wr4.z, wr4.w};
#pragma unroll
      for (int i = 0; i < 4; ++i)
#pragma unroll
        for (int j = 0; j < 4; ++j)
          acc[i][j] = fmaf(ar[i], wr[j], acc[i][j]);
    }
  }
#pragma unroll
  for (int i = 0; i < 4; ++i) {
    const int r = rowBase + 4 * ty + i;
    const int c0 = colBase + 4 * tx;
    float4 v;
    float* vp = &v.x;
#pragma unroll
    for (int j = 0; j < 4; ++j) vp[j] = gelu_f(acc[i][j] + bias[c0 + j]);
    *(float4*)(C + (size_t)r * N + c0) = v;
  }
}

// --- gather chosen code + commit MSE. z_e reconstructed from split (ah+al).
__global__ void gather_commit_kernel(const unsigned short* __restrict__ split,
                                     const float* __restrict__ cb,
                                     const u64* __restrict__ mk,
                                     float* __restrict__ qbuf, float* out_q,
                                     float* out_idx, float* sumptr, int K) {
  const int w = threadIdx.x >> 6, lane = threadIdx.x & 63;
  const int row = blockIdx.x * 4 + w;
  const u64 key = mk[row];
  const int idx = (int)(unsigned)(key & 0xFFFFFFFFULL);
  if (lane == 0) out_idx[row] = (float)idx;
  float local = 0.f;
  const unsigned short* sp = split + (size_t)row * 3 * K;
  for (int c = lane; c < K; c += 64) {
    const float ze = bf16_to_f(sp[c]) + bf16_to_f(sp[c + K]);
    const float v = cb[(size_t)idx * K + c];
    qbuf[(size_t)row * K + c] = v;
    out_q[(size_t)row * K + c] = v;
    const float d = ze - v;
    local += d * d;
  }
#pragma unroll
  for (int o = 32; o > 0; o >>= 1) local += __shfl_down(local, o);
  __shared__ float p[4];
  if (lane == 0) p[w] = local;
  __syncthreads();
  if (threadIdx.x == 0) atomicAdd(sumptr, p[0] + p[1] + p[2] + p[3]);
}

__global__ void finalize_kernel(const float* __restrict__ sums,
                                float* __restrict__ out) {
  const float cz = sums[0] / ((float)kBatch * 256.f);
  const float cq = sums[1] / ((float)kBatch * 128.f);
  const float rec = sums[2] / ((float)kBatch * 512.f);
  out[0] = rec + 0.5f * cz + 0.5f * cq;
  out[1] = rec;
  out[2] = cz;
  out[3] = cz;
  out[4] = cq;
  out[5] = cq;
}

}  // namespace

extern "C" void kernel_launch(void* const* d_in, const int* in_sizes, int n_in,
                              void* d_out, int out_size, void* d_ws,
                              size_t ws_size, hipStream_t stream) {
  const float* x   = (const float*)d_in[0];
  const float* eW1 = (const float*)d_in[1];
  const float* eb1 = (const float*)d_in[2];
  const float* eW2 = (const float*)d_in[3];
  const float* eb2 = (const float*)d_in[4];
  const float* zW  = (const float*)d_in[5];
  const float* zb  = (const float*)d_in[6];
  const float* zci = (const float*)d_in[7];
  const float* zcb = (const float*)d_in[8];
  const float* qW  = (const float*)d_in[9];
  const float* qb  = (const float*)d_in[10];
  const float* qci = (const float*)d_in[11];
  const float* qcb = (const float*)d_in[12];
  const float* dW1 = (const float*)d_in[13];
  const float* db1 = (const float*)d_in[14];
  const float* dW2 = (const float*)d_in[15];
  const float* db2 = (const float*)d_in[16];
  const float* oW  = (const float*)d_in[17];
  const float* ob  = (const float*)d_in[18];

  float* out = (float*)d_out;
  float* out_xr = out + 6;
  float* out_zq = out_xr + (size_t)32768 * 512;
  float* out_qq = out_zq + (size_t)32768 * 256;
  float* out_zi = out_qq + (size_t)32768 * 128;
  float* out_qi = out_zi + 32768;

  // workspace layout (~121 MB, time-windowed aliasing into the h region):
  char* wsb = (char*)d_ws;
  float* zWn  = (float*)(wsb + 0x0000000);                   // 512 KB
  float* qWn  = (float*)(wsb + 0x0080000);                   // 128 KB
  float* zcbn = (float*)(wsb + 0x00A0000);                   // 16 KB
  float* qcbn = (float*)(wsb + 0x00A4000);                   // 8 KB
  float* sums = (float*)(wsb + 0x00A6000);                   // 3 floats
  u64*  mkz   = (u64*) (wsb + 0x00A8000);                    // 256 KB
  u64*  mkq   = (u64*) (wsb + 0x00E8000);                    // 256 KB
  unsigned short* zcbs = (unsigned short*)(wsb + 0x0128000); // 6 MB [prep -> z-dist]
  unsigned short* qcbs = (unsigned short*)(wsb + 0x0728000); // 1.5 MB [prep -> q-dist]
  // 0x08A8000: h1 (8 MB) [enc1->enc2], [dec1->dec2]
  //            zsplit (48 MB) [z-proj -> gather_z]  (aliases h1 dead window)
  float* h1            = (float*)(wsb + 0x08A8000);
  unsigned short* zspl = (unsigned short*)(wsb + 0x08A8000);
  // 0x38A8000: h (64 MB) [enc2 -> z-proj], [dec2 -> out]
  //   aliases: zq @+0 (32 MB) [gather_z -> q-proj]
  //            qsplit @+32M (24 MB) [q-proj -> q-dist]
  //            qe @+0 (16 MB) [gather_q -> dec1]
  float* h             = (float*)(wsb + 0x38A8000);
  float* zq            = (float*)(wsb + 0x38A8000);
  unsigned short* qspl = (unsigned short*)(wsb + 0x38A8000 + 0x2000000);
  float* qe            = (float*)(wsb + 0x38A8000);

  hipMemsetAsync(mkz, 0xFF, (size_t)32768 * 8, stream);
  hipMemsetAsync(mkq, 0xFF, (size_t)32768 * 8, stream);
  hipMemsetAsync(sums, 0, 3 * sizeof(float), stream);

  // weight / codebook prep
  norm_rows_kernel<<<256, 256, 0, stream>>>(zW, zci, zWn, 512);
  norm_rows_kernel<<<128, 256, 0, stream>>>(qW, qci, qWn, 256);
  cb_norm_kernel<<<1024, 256, 0, stream>>>(zcb, zcbn, 256);
  cb_norm_kernel<<<512, 256, 0, stream>>>(qcb, qcbn, 128);
  split_cb_kernel<<<4096, 256, 0, stream>>>(zcb, zcbs, 256, 8, 4096 * 256);
  split_cb_kernel<<<1024, 256, 0, stream>>>(qcb, qcbs, 128, 7, 2048 * 128);

  // encoder
  gemm_small_gelu<<<dim3(1, 512), 256, 0, stream>>>(x, eW1, eb1, h1, 512, 64);
  gemm_big<MODE_GELU><<<dim3(4, 256), 256, 0, stream>>>(
      h1, eW2, eb2, h, nullptr, nullptr, 64, 512);
  gemm_big<MODE_SIGMOID><<<dim3(2, 256), 256, 0, stream>>>(
      h, zWn, zb, (float*)zspl, nullptr, nullptr, 512, 256);

  // z quantize (MFMA)
  dist_mfma<<<dim3(32, 256), 256, 0, stream>>>(zspl, zcbs, zcbn, mkz, 768);
  gather_commit_kernel<<<8192, 256, 0, stream>>>(zspl, zcb, mkz, zq, out_zq,
                                                 out_zi, &sums[0], 256);

  // q level
  gemm_big<MODE_SIGMOID><<<dim3(1, 256), 256, 0, stream>>>(
      zq, qWn, qb, (float*)qspl, nullptr, nullptr, 256, 128);
  dist_mfma<<<dim3(16, 256), 256, 0, stream>>>(qspl, qcbs, qcbn, mkq, 384);
  gather_commit_kernel<<<8192, 256, 0, stream>>>(qspl, qcb, mkq, qe, out_qq,
                                                 out_qi, &sums[1], 128);

  // decoder
  gemm_small_gelu<<<dim3(1, 512), 256, 0, stream>>>(qe, dW1, db1, h1, 128, 64);
  gemm_big<MODE_GELU><<<dim3(4, 256), 256, 0, stream>>>(
      h1, dW2, db2, h, nullptr, nullptr, 64, 512);
  gemm_big<MODE_RECON><<<dim3(4, 256), 256, 0, stream>>>(
      h, oW, ob, out_xr, x, &sums[2], 512, 512);

  finalize_kernel<<<1, 1, 0, stream>>>(sums, out);

  (void)in_sizes; (void)n_in; (void)out_size; (void)ws_size;
}

// Round 3
// 1173.229 us; speedup vs baseline: 1.5600x; 1.0648x over previous
//
#include <hip/hip_runtime.h>

typedef unsigned long long u64;
typedef unsigned short u16;

// ---------------------------------------------------------------------------
// HierarchicalLFQHVQVAE forward — R3.
// - Quantize: two-stage. Stage1 = plain bf16 MFMA dists, best-2 per 128-col
//   block (no atomics). Stage2 = top-8 of candidates, exact f32 re-rank,
//   fused gather + commit-MSE + idx write.
// - Projections (enc2, z-proj, q-proj): f32 A split to (hi,lo) bf16 in-kernel,
//   3-term MFMA (ah.bh + al.bh + ah.bl) vs pre-split weights -> f32-accurate.
// - Decoder (dec1, dec2, recon): plain bf16 MFMA (error ~1e-2 << thresholds).
// - enc1 stays f32 VALU (tiny, input is f32).
// ---------------------------------------------------------------------------

namespace {

constexpr int kBatch = 32768;

__device__ __forceinline__ float gelu_f(float x) {
  return 0.5f * x * (1.0f + erff(x * 0.70710678118654752440f));
}
__device__ __forceinline__ float sigmoid_f(float x) {
  return 1.0f / (1.0f + expf(-x));
}
__device__ __forceinline__ u64 pack_key(float d, unsigned j) {
  unsigned u = __float_as_uint(d);
  u = (u & 0x80000000u) ? ~u : (u | 0x80000000u);
  return ((u64)u << 32) | j;
}
__device__ __forceinline__ u16 bf16_rne(float x) {
  unsigned u = __float_as_uint(x);
  unsigned r = (u + 0x7FFFu + ((u >> 16) & 1u)) >> 16;
  return (u16)r;
}
__device__ __forceinline__ float bf16_to_f(u16 h) {
  return __uint_as_float((unsigned)h << 16);
}
__device__ __forceinline__ u64 min64(u64 a, u64 b) { return a < b ? a : b; }
__device__ __forceinline__ u64 max64(u64 a, u64 b) { return a > b ? a : b; }

__device__ __forceinline__ void load_lds16(const void* g, void* l) {
  __builtin_amdgcn_global_load_lds(
      (const __attribute__((address_space(1))) void*)g,
      (__attribute__((address_space(3))) void*)l, 16, 0, 0);
}

typedef short bf16x8 __attribute__((ext_vector_type(8)));
typedef float f32x4 __attribute__((ext_vector_type(4)));

// ===========================================================================
// Prep kernels
// ===========================================================================

// codebook squared norms, f64 accumulate (exact ranking reference)
__global__ void cb_norm_kernel(const float* __restrict__ cb,
                               float* __restrict__ cbn, int K) {
  const int row = blockIdx.x * 4 + (threadIdx.x >> 6);
  const int lane = threadIdx.x & 63;
  double s = 0.0;
  for (int k = lane; k < K; k += 64) {
    const float v = cb[(size_t)row * K + k];
    s += (double)v * (double)v;
  }
#pragma unroll
  for (int o = 32; o > 0; o >>= 1) s += __shfl_down(s, o);
  if (lane == 0) cbn[row] = (float)s;
}

// all plain bf16 casts in one launch
__global__ void cast_all_kernel(const float* zcb, u16* zcbh, const float* qcb,
                                u16* qcbh, const float* dW1, u16* dW1b,
                                const float* dW2, u16* dW2b, const float* oW,
                                u16* oWb) {
  const int stride = gridDim.x * 256;
  const int t0 = blockIdx.x * 256 + threadIdx.x;
  for (int i = t0; i < 4096 * 256; i += stride) zcbh[i] = bf16_rne(zcb[i]);
  for (int i = t0; i < 2048 * 128; i += stride) qcbh[i] = bf16_rne(qcb[i]);
  for (int i = t0; i < 64 * 128; i += stride) dW1b[i] = bf16_rne(dW1[i]);
  for (int i = t0; i < 512 * 64; i += stride) dW2b[i] = bf16_rne(dW2[i]);
  for (int i = t0; i < 512 * 512; i += stride) oWb[i] = bf16_rne(oW[i]);
}

// Lipschitz row norm + split to [wh(K) | wl(K)] (row stride 2K)
__global__ void norm_split_kernel(const float* __restrict__ W,
                                  const float* __restrict__ ci,
                                  u16* __restrict__ D, int K) {
  const int row = blockIdx.x;
  const int tid = threadIdx.x;
  float s = 0.f;
  for (int k = tid; k < K; k += 256) s += fabsf(W[(size_t)row * K + k]);
#pragma unroll
  for (int o = 32; o > 0; o >>= 1) s += __shfl_down(s, o);
  __shared__ float p[4];
  if ((tid & 63) == 0) p[tid >> 6] = s;
  __syncthreads();
  const float tot = p[0] + p[1] + p[2] + p[3];
  const float c = ci[row];
  const float sp = (c > 20.f) ? c : log1pf(expf(c));
  const float scale = fminf(1.f, sp / tot);
  for (int k = tid; k < K; k += 256) {
    const float v = W[(size_t)row * K + k] * scale;
    const u16 h = bf16_rne(v);
    const u16 l = bf16_rne(v - bf16_to_f(h));
    D[(size_t)row * 2 * K + k] = h;
    D[(size_t)row * 2 * K + K + k] = l;
  }
}

// plain split to [wh|wl] (eW2: 512 rows x K=64)
__global__ void split2_kernel(const float* __restrict__ W, u16* __restrict__ D,
                              int kshift, int total) {
  const int i = blockIdx.x * 256 + threadIdx.x;
  if (i >= total) return;
  const int K = 1 << kshift;
  const int r = i >> kshift, k = i & (K - 1);
  const float v = W[i];
  const u16 h = bf16_rne(v);
  const u16 l = bf16_rne(v - bf16_to_f(h));
  D[(size_t)r * 2 * K + k] = h;
  D[(size_t)r * 2 * K + K + k] = l;
}

// ===========================================================================
// enc1: f32 VALU 64x64-tile GEMM + GELU (proven R2 kernel)
// ===========================================================================
__global__ __launch_bounds__(256, 4) void gemm_small_gelu(
    const float* __restrict__ A, const float* __restrict__ W,
    const float* __restrict__ bias, float* __restrict__ C, int K, int N) {
  __shared__ __align__(16) float As[16][68];
  __shared__ __align__(16) float Ws[16][68];
  const int tid = threadIdx.x;
  const int tx = tid & 15, ty = tid >> 4;
  const int rowBase = blockIdx.y * 64;
  const int colBase = blockIdx.x * 64;
  const int lrow = tid >> 2;
  const int lk = (tid & 3) * 4;
  float acc[4][4] = {};
  const float* Aptr = A + (size_t)(rowBase + lrow) * K + lk;
  const float* Wptr = W + (size_t)(colBase + lrow) * K + lk;
  for (int k0 = 0; k0 < K; k0 += 16) {
    const float4 a = *(const float4*)(Aptr + k0);
    const float4 wv = *(const float4*)(Wptr + k0);
    __syncthreads();
    As[lk + 0][lrow] = a.x; As[lk + 1][lrow] = a.y;
    As[lk + 2][lrow] = a.z; As[lk + 3][lrow] = a.w;
    Ws[lk + 0][lrow] = wv.x; Ws[lk + 1][lrow] = wv.y;
    Ws[lk + 2][lrow] = wv.z; Ws[lk + 3][lrow] = wv.w;
    __syncthreads();
#pragma unroll
    for (int kk = 0; kk < 16; ++kk) {
      const float4 av = *(const float4*)&As[kk][4 * ty];
      const float4 wr4 = *(const float4*)&Ws[kk][4 * tx];
      const float ar[4] = {av.x, av.y, av.z, av.w};
      const float wr[4] = {wr4.x, wr4.y, wr4.z, wr4.w};
#pragma unroll
      for (int i = 0; i < 4; ++i)
#pragma unroll
        for (int j = 0; j < 4; ++j)
          acc[i][j] = fmaf(ar[i], wr[j], acc[i][j]);
    }
  }
#pragma unroll
  for (int i = 0; i < 4; ++i) {
    const int r = rowBase + 4 * ty + i;
    const int c0 = colBase + 4 * tx;
    float4 v;
    float* vp = &v.x;
#pragma unroll
    for (int j = 0; j < 4; ++j) vp[j] = gelu_f(acc[i][j] + bias[c0 + j]);
    *(float4*)(C + (size_t)r * N + c0) = v;
  }
}

// ===========================================================================
// Plain bf16 MFMA GEMM. A [M][Ktot] bf16, B [N][Ktot] bf16 (row-major).
// TM x TN tile, 4 waves of 64x64 (4x4 MFMA 16x16x32). XOR-swizzled LDS.
// Modes: GELU->bf16 store | RECON (f32 store + MSE) | DIST2 (best-2/block).
// ===========================================================================
enum { M_GELU_B16 = 0, M_RECON = 1, M_DIST2 = 2 };

template <int TM, int TN, int MODE>
__global__ __launch_bounds__(256) void gemm_bf16(
    const u16* __restrict__ A, const u16* __restrict__ B,
    const float* __restrict__ bias, void* __restrict__ Cv,
    const float* __restrict__ X, float* __restrict__ sumptr, int Ktot, int N) {
  __shared__ __align__(16) u16 As[TM * 64];
  __shared__ __align__(16) u16 Bs[TN * 64];
  constexpr int AIT = (TM * 8) / 256;
  constexpr int BIT = (TN * 8) / 256;
  const int tid = threadIdx.x;
  const int lane = tid & 63, w = tid >> 6;
  const int quad = lane >> 4, l15 = lane & 15;
  const int waveM = (TN == 128) ? (w & 1) * 64 : w * 64;
  const int waveN = (TN == 128) ? (w >> 1) * 64 : 0;
  const int rowBase = blockIdx.y * TM;
  const int colBase = blockIdx.x * TN;

  f32x4 acc[4][4] = {};

  for (int k0 = 0; k0 < Ktot; k0 += 64) {
    __syncthreads();
#pragma unroll
    for (int i = 0; i < AIT; ++i) {
      const int ch = i * 256 + tid;
      const int r = ch >> 3, c = ch & 7, g = c ^ (r & 7);
      load_lds16(A + (size_t)(rowBase + r) * Ktot + k0 + g * 8,
                 (char*)As + ch * 16);
    }
#pragma unroll
    for (int i = 0; i < BIT; ++i) {
      const int ch = i * 256 + tid;
      const int r = ch >> 3, c = ch & 7, g = c ^ (r & 7);
      load_lds16(B + (size_t)(colBase + r) * Ktot + k0 + g * 8,
                 (char*)Bs + ch * 16);
    }
    __syncthreads();
#pragma unroll
    for (int ks = 0; ks < 2; ++ks) {
      bf16x8 af[4], bf[4];
      const int ch = ks * 4 + quad;
#pragma unroll
      for (int mi = 0; mi < 4; ++mi) {
        const int rl = waveM + mi * 16 + l15;
        af[mi] = *(const bf16x8*)(As + rl * 64 + (ch ^ (rl & 7)) * 8);
      }
#pragma unroll
      for (int ni = 0; ni < 4; ++ni) {
        const int rl = waveN + ni * 16 + l15;
        bf[ni] = *(const bf16x8*)(Bs + rl * 64 + (ch ^ (rl & 7)) * 8);
      }
#pragma unroll
      for (int mi = 0; mi < 4; ++mi)
#pragma unroll
        for (int ni = 0; ni < 4; ++ni)
          acc[mi][ni] = __builtin_amdgcn_mfma_f32_16x16x32_bf16(
              af[mi], bf[ni], acc[mi][ni], 0, 0, 0);
    }
  }

  if constexpr (MODE == M_GELU_B16) {
    u16* C = (u16*)Cv;
#pragma unroll
    for (int mi = 0; mi < 4; ++mi)
#pragma unroll
      for (int r = 0; r < 4; ++r) {
        const int row = rowBase + waveM + mi * 16 + quad * 4 + r;
#pragma unroll
        for (int ni = 0; ni < 4; ++ni) {
          const int col = colBase + waveN + ni * 16 + l15;
          C[(size_t)row * N + col] =
              bf16_rne(gelu_f(acc[mi][ni][r] + bias[col]));
        }
      }
  } else if constexpr (MODE == M_RECON) {
    float* C = (float*)Cv;
    float local = 0.f;
#pragma unroll
    for (int mi = 0; mi < 4; ++mi)
#pragma unroll
      for (int r = 0; r < 4; ++r) {
        const int row = rowBase + waveM + mi * 16 + quad * 4 + r;
#pragma unroll
        for (int ni = 0; ni < 4; ++ni) {
          const int col = colBase + waveN + ni * 16 + l15;
          const float val = acc[mi][ni][r] + bias[col];
          const float d = val - X[(size_t)row * N + col];
          local += d * d;
          C[(size_t)row * N + col] = val;
        }
      }
#pragma unroll
    for (int o = 32; o > 0; o >>= 1) local += __shfl_down(local, o);
    __shared__ float psum[4];
    if (lane == 0) psum[w] = local;
    __syncthreads();
    if (tid == 0) atomicAdd(sumptr, psum[0] + psum[1] + psum[2] + psum[3]);
  } else {  // M_DIST2: best-2 per (row, col-block) -> cand[row][2*gridDim.x]
    float cn[4];
#pragma unroll
    for (int ni = 0; ni < 4; ++ni)
      cn[ni] = bias[colBase + waveN + ni * 16 + l15];
    __shared__ u64 wred[2][128][2];
#pragma unroll
    for (int mi = 0; mi < 4; ++mi)
#pragma unroll
      for (int r = 0; r < 4; ++r) {
        u64 b0 = ~0ull, b1 = ~0ull;
#pragma unroll
        for (int ni = 0; ni < 4; ++ni) {
          const unsigned col = colBase + waveN + ni * 16 + l15;
          const u64 key = pack_key(cn[ni] - 2.0f * acc[mi][ni][r], col);
          if (key < b0) { b1 = b0; b0 = key; }
          else if (key < b1) { b1 = key; }
        }
#pragma unroll
        for (int off = 1; off < 16; off <<= 1) {
          const u64 o0 = __shfl_xor(b0, off);
          const u64 o1 = __shfl_xor(b1, off);
          const u64 n0 = min64(b0, o0);
          const u64 n1 = min64(max64(b0, o0), min64(b1, o1));
          b0 = n0; b1 = n1;
        }
        if (l15 == 0) {
          const int rl = waveM + mi * 16 + quad * 4 + r;
          wred[w >> 1][rl][0] = b0;
          wred[w >> 1][rl][1] = b1;
        }
      }
    __syncthreads();
    if (tid < 128) {
      const u64 a0 = wred[0][tid][0], a1 = wred[0][tid][1];
      const u64 c0 = wred[1][tid][0], c1 = wred[1][tid][1];
      const u64 b0 = min64(a0, c0);
      const u64 b1 = min64(max64(a0, c0), min64(a1, c1));
      u64* cand = (u64*)Cv;
      const size_t base =
          (size_t)(rowBase + tid) * (2 * gridDim.x) + 2 * blockIdx.x;
      cand[base] = b0;
      cand[base + 1] = b1;
    }
  }
}

// ===========================================================================
// Split-f32 MFMA GEMM: A f32 [M][K] split in-kernel to (hi,lo) bf16 LDS
// tiles; B pre-split [N][2K] = [wh|wl]. acc += ah.bh + al.bh + ah.bl.
// 128x128 tile. Modes: GELU->f32 | SIGMOID->f32 + bf16 aux.
// ===========================================================================
enum { S_GELU_F32 = 0, S_SIG_ZE = 1 };

template <int MODE>
__global__ __launch_bounds__(256) void gemm_sf32(
    const float* __restrict__ A, const u16* __restrict__ B2,
    const float* __restrict__ bias, float* __restrict__ C,
    u16* __restrict__ Caux, int K, int N) {
  __shared__ __align__(16) u16 Ah[128 * 64];
  __shared__ __align__(16) u16 Al[128 * 64];
  __shared__ __align__(16) u16 Bh[128 * 64];
  __shared__ __align__(16) u16 Bl[128 * 64];
  const int tid = threadIdx.x;
  const int lane = tid & 63, w = tid >> 6;
  const int quad = lane >> 4, l15 = lane & 15;
  const int waveM = (w & 1) * 64, waveN = (w >> 1) * 64;
  const int rowBase = blockIdx.y * 128;
  const int colBase = blockIdx.x * 128;

  f32x4 acc[4][4] = {};

  for (int k0 = 0; k0 < K; k0 += 64) {
    __syncthreads();
    // B staging: async direct-to-LDS from pre-split weights
#pragma unroll
    for (int i = 0; i < 4; ++i) {
      const int ch = i * 256 + tid;
      const int r = ch >> 3, c = ch & 7, g = c ^ (r & 7);
      const size_t rb = (size_t)(colBase + r) * 2 * K + k0 + g * 8;
      load_lds16(B2 + rb, (char*)Bh + ch * 16);
      load_lds16(B2 + rb + K, (char*)Bl + ch * 16);
    }
    // A staging: f32 load -> split -> ds_write (overlaps with B loads)
#pragma unroll
    for (int i = 0; i < 8; ++i) {
      const int ch = i * 256 + tid;          // 128 rows x 16 float4-chunks
      const int r = ch >> 4, c4 = ch & 15;
      const float4 v = *(const float4*)(A + (size_t)(rowBase + r) * K + k0 + c4 * 4);
      u16 hv[4], lv[4];
      const float vv[4] = {v.x, v.y, v.z, v.w};
#pragma unroll
      for (int j = 0; j < 4; ++j) {
        hv[j] = bf16_rne(vv[j]);
        lv[j] = bf16_rne(vv[j] - bf16_to_f(hv[j]));
      }
      const int g = (c4 >> 1) ^ (r & 7);
      const int off = r * 64 + g * 8 + (c4 & 1) * 4;  // element index
      *(ushort4*)(Ah + off) = make_ushort4(hv[0], hv[1], hv[2], hv[3]);
      *(ushort4*)(Al + off) = make_ushort4(lv[0], lv[1], lv[2], lv[3]);
    }
    __syncthreads();
#pragma unroll
    for (int ks = 0; ks < 2; ++ks) {
      bf16x8 ahf[4], alf[4], bhf[4], blf[4];
      const int ch = ks * 4 + quad;
#pragma unroll
      for (int mi = 0; mi < 4; ++mi) {
        const int rl = waveM + mi * 16 + l15;
        const int so = rl * 64 + (ch ^ (rl & 7)) * 8;
        ahf[mi] = *(const bf16x8*)(Ah + so);
        alf[mi] = *(const bf16x8*)(Al + so);
      }
#pragma unroll
      for (int ni = 0; ni < 4; ++ni) {
        const int rl = waveN + ni * 16 + l15;
        const int so = rl * 64 + (ch ^ (rl & 7)) * 8;
        bhf[ni] = *(const bf16x8*)(Bh + so);
        blf[ni] = *(const bf16x8*)(Bl + so);
      }
#pragma unroll
      for (int mi = 0; mi < 4; ++mi)
#pragma unroll
        for (int ni = 0; ni < 4; ++ni) {
          acc[mi][ni] = __builtin_amdgcn_mfma_f32_16x16x32_bf16(
              ahf[mi], bhf[ni], acc[mi][ni], 0, 0, 0);
          acc[mi][ni] = __builtin_amdgcn_mfma_f32_16x16x32_bf16(
              alf[mi], bhf[ni], acc[mi][ni], 0, 0, 0);
          acc[mi][ni] = __builtin_amdgcn_mfma_f32_16x16x32_bf16(
              ahf[mi], blf[ni], acc[mi][ni], 0, 0, 0);
        }
    }
  }

#pragma unroll
  for (int mi = 0; mi < 4; ++mi)
#pragma unroll
    for (int r = 0; r < 4; ++r) {
      const int row = rowBase + waveM + mi * 16 + quad * 4 + r;
#pragma unroll
      for (int ni = 0; ni < 4; ++ni) {
        const int col = colBase + waveN + ni * 16 + l15;
        const float pre = acc[mi][ni][r] + bias[col];
        if constexpr (MODE == S_GELU_F32) {
          C[(size_t)row * N + col] = gelu_f(pre);
        } else {
          const float s = sigmoid_f(pre);
          C[(size_t)row * N + col] = s;
          Caux[(size_t)row * N + col] = bf16_rne(s);
        }
      }
    }
}

// ===========================================================================
// Stage-2: per-row (one wave) top-8 of NC candidates -> exact f32 re-rank ->
// gather + commit MSE + idx. LEVEL 0: also writes z_q f32 ws (for q-proj).
// LEVEL 1: also writes q_q bf16 (for dec1).
// ===========================================================================
template <int K, int NC, int LEVEL>
__global__ __launch_bounds__(256) void rerank_kernel(
    const u64* __restrict__ cand, const float* __restrict__ ze,
    const float* __restrict__ cb, const float* __restrict__ cbn,
    float* __restrict__ outq, float* __restrict__ wsq,
    u16* __restrict__ wsqb, float* __restrict__ out_idx,
    float* __restrict__ sumptr) {
  const int w = threadIdx.x >> 6, lane = threadIdx.x & 63;
  const int row = blockIdx.x * 4 + w;

  u64 key = (lane < NC) ? cand[(size_t)row * NC + lane] : ~0ull;
  unsigned topidx[8];
#pragma unroll
  for (int t = 0; t < 8; ++t) {
    u64 m = key;
#pragma unroll
    for (int off = 1; off < 64; off <<= 1) m = min64(m, __shfl_xor(m, off));
    topidx[t] = (unsigned)m;
    if (key == m) key = ~0ull;
  }

  const int g = lane >> 3, sub = lane & 7;
  unsigned ci = topidx[0];
#pragma unroll
  for (int t = 1; t < 8; ++t) ci = (g == t) ? topidx[t] : ci;

  const float* zr = ze + (size_t)row * K;
  const float* cr = cb + (size_t)ci * K;
  float dot = 0.f;
#pragma unroll
  for (int k = sub * (K / 8); k < (sub + 1) * (K / 8); k += 4) {
    const float4 zv = *(const float4*)(zr + k);
    const float4 cv = *(const float4*)(cr + k);
    dot = fmaf(zv.x, cv.x, dot);
    dot = fmaf(zv.y, cv.y, dot);
    dot = fmaf(zv.z, cv.z, dot);
    dot = fmaf(zv.w, cv.w, dot);
  }
#pragma unroll
  for (int off = 1; off < 8; off <<= 1) dot += __shfl_xor(dot, off);
  u64 k2 = pack_key(cbn[ci] - 2.0f * dot, ci);
#pragma unroll
  for (int off = 8; off < 64; off <<= 1) k2 = min64(k2, __shfl_xor(k2, off));
  const unsigned best = (unsigned)k2;
  if (lane == 0) out_idx[row] = (float)best;

  // gather + commit
  const float* br = cb + (size_t)best * K;
  float local = 0.f;
  for (int c = lane; c < K; c += 64) {
    const float v = br[c];
    const float z = zr[c];
    const float d = z - v;
    local += d * d;
    outq[(size_t)row * K + c] = v;
    if (LEVEL == 0) wsq[(size_t)row * K + c] = v;
    else wsqb[(size_t)row * K + c] = bf16_rne(v);
  }
#pragma unroll
  for (int o = 32; o > 0; o >>= 1) local += __shfl_down(local, o);
  __shared__ float p[4];
  if (lane == 0) p[w] = local;
  __syncthreads();
  if (threadIdx.x == 0) atomicAdd(sumptr, p[0] + p[1] + p[2] + p[3]);
}

__global__ void finalize_kernel(const float* __restrict__ sums,
                                float* __restrict__ out) {
  const float cz = sums[0] / ((float)kBatch * 256.f);
  const float cq = sums[1] / ((float)kBatch * 128.f);
  const float rec = sums[2] / ((float)kBatch * 512.f);
  out[0] = rec + 0.5f * cz + 0.5f * cq;
  out[1] = rec;
  out[2] = cz;
  out[3] = cz;
  out[4] = cq;
  out[5] = cq;
}

}  // namespace

extern "C" void kernel_launch(void* const* d_in, const int* in_sizes, int n_in,
                              void* d_out, int out_size, void* d_ws,
                              size_t ws_size, hipStream_t stream) {
  const float* x   = (const float*)d_in[0];
  const float* eW1 = (const float*)d_in[1];
  const float* eb1 = (const float*)d_in[2];
  const float* eW2 = (const float*)d_in[3];
  const float* eb2 = (const float*)d_in[4];
  const float* zW  = (const float*)d_in[5];
  const float* zb  = (const float*)d_in[6];
  const float* zci = (const float*)d_in[7];
  const float* zcb = (const float*)d_in[8];
  const float* qW  = (const float*)d_in[9];
  const float* qb  = (const float*)d_in[10];
  const float* qci = (const float*)d_in[11];
  const float* qcb = (const float*)d_in[12];
  const float* dW1 = (const float*)d_in[13];
  const float* db1 = (const float*)d_in[14];
  const float* dW2 = (const float*)d_in[15];
  const float* db2 = (const float*)d_in[16];
  const float* oW  = (const float*)d_in[17];
  const float* ob  = (const float*)d_in[18];

  float* out = (float*)d_out;
  float* out_xr = out + 6;
  float* out_zq = out_xr + (size_t)32768 * 512;
  float* out_qq = out_zq + (size_t)32768 * 256;
  float* out_zi = out_qq + (size_t)32768 * 128;
  float* out_qi = out_zi + 32768;

  // ---- workspace layout (high-water 0x7C00000 = 124 MiB) -----------------
  char* wsb = (char*)d_ws;
  u16*  zWns = (u16*) (wsb + 0x0000000);  // 256x1024  512K
  u16*  qWns = (u16*) (wsb + 0x0080000);  // 128x512   128K
  u16*  eW2s = (u16*) (wsb + 0x00A0000);  // 512x128   128K
  u16*  dW1b = (u16*) (wsb + 0x00C0000);  // 64x128     16K
  u16*  dW2b = (u16*) (wsb + 0x00C4000);  // 512x64     64K
  u16*  oWb  = (u16*) (wsb + 0x00D4000);  // 512x512   512K
  u16*  zcbh = (u16*) (wsb + 0x0154000);  // 4096x256    2M
  u16*  qcbh = (u16*) (wsb + 0x0354000);  // 2048x128  512K
  float* zcbn = (float*)(wsb + 0x03D4000); // 16K
  float* qcbn = (float*)(wsb + 0x03D8000); // 8K
  float* sums = (float*)(wsb + 0x03DA000); // 3 floats
  // time-windowed regions:
  float* h1   = (float*)(wsb + 0x0400000); // 8M  [enc1->enc2]
  u64*  candq = (u64*)  (wsb + 0x0400000); //   8M  [q-dist1 -> q-rerank]
  u16*  h1b   = (u16*)  (wsb + 0x0400000); //   4M  [dec1 -> dec2]
  float* ze   = (float*)(wsb + 0x0C00000); // 32M [z-proj -> z-rerank]
  u16*  hb    = (u16*)  (wsb + 0x0C00000); //   32M [dec2 -> recon]
  u16*  zeb   = (u16*)  (wsb + 0x2C00000); // 16M [z-proj -> z-dist1]
  float* qe   = (float*)(wsb + 0x2C00000); //   16M [q-proj -> q-rerank]
  float* h    = (float*)(wsb + 0x3C00000); // 64M [enc2 -> z-proj]
  u64*  candz = (u64*)  (wsb + 0x3C00000); //   16M [z-dist1 -> z-rerank]
  float* zqws = (float*)(wsb + 0x4C00000); //   32M [z-rerank -> q-proj]
  u16*  qeb   = (u16*)  (wsb + 0x6C00000); //   8M  [q-proj -> q-dist1]
  u16*  qqb   = (u16*)  (wsb + 0x7400000); //   8M  [q-rerank -> dec1]

  hipMemsetAsync(sums, 0, 3 * sizeof(float), stream);

  // ---- prep ----
  cb_norm_kernel<<<1024, 256, 0, stream>>>(zcb, zcbn, 256);
  cb_norm_kernel<<<512, 256, 0, stream>>>(qcb, qcbn, 128);
  cast_all_kernel<<<512, 256, 0, stream>>>(zcb, zcbh, qcb, qcbh, dW1, dW1b,
                                           dW2, dW2b, oW, oWb);
  norm_split_kernel<<<256, 256, 0, stream>>>(zW, zci, zWns, 512);
  norm_split_kernel<<<128, 256, 0, stream>>>(qW, qci, qWns, 256);
  split2_kernel<<<128, 256, 0, stream>>>(eW2, eW2s, 6, 512 * 64);

  // ---- encoder ----
  gemm_small_gelu<<<dim3(1, 512), 256, 0, stream>>>(x, eW1, eb1, h1, 512, 64);
  gemm_sf32<S_GELU_F32><<<dim3(4, 256), 256, 0, stream>>>(
      h1, eW2s, eb2, h, nullptr, 64, 512);
  gemm_sf32<S_SIG_ZE><<<dim3(2, 256), 256, 0, stream>>>(
      h, zWns, zb, ze, zeb, 512, 256);

  // ---- z quantize ----
  gemm_bf16<128, 128, M_DIST2><<<dim3(32, 256), 256, 0, stream>>>(
      zeb, zcbh, zcbn, candz, nullptr, nullptr, 256, 4096);
  rerank_kernel<256, 64, 0><<<8192, 256, 0, stream>>>(
      candz, ze, zcb, zcbn, out_zq, zqws, nullptr, out_zi, &sums[0]);

  // ---- q level ----
  gemm_sf32<S_SIG_ZE><<<dim3(1, 256), 256, 0, stream>>>(
      zqws, qWns, qb, qe, qeb, 256, 128);
  gemm_bf16<128, 128, M_DIST2><<<dim3(16, 256), 256, 0, stream>>>(
      qeb, qcbh, qcbn, candq, nullptr, nullptr, 128, 2048);
  rerank_kernel<128, 32, 1><<<8192, 256, 0, stream>>>(
      candq, qe, qcb, qcbn, out_qq, nullptr, qqb, out_qi, &sums[1]);

  // ---- decoder ----
  gemm_bf16<256, 64, M_GELU_B16><<<dim3(1, 128), 256, 0, stream>>>(
      qqb, dW1b, db1, h1b, nullptr, nullptr, 128, 64);
  gemm_bf16<128, 128, M_GELU_B16><<<dim3(4, 256), 256, 0, stream>>>(
      h1b, dW2b, db2, hb, nullptr, nullptr, 64, 512);
  gemm_bf16<128, 128, M_RECON><<<dim3(4, 256), 256, 0, stream>>>(
      hb, oWb, ob, out_xr, x, &sums[2], 512, 512);

  finalize_kernel<<<1, 1, 0, stream>>>(sums, out);

  (void)in_sizes; (void)n_in; (void)out_size; (void)ws_size;
}

// Round 4
// 887.312 us; speedup vs baseline: 2.0626x; 1.3222x over previous
//
#include <hip/hip_runtime.h>

typedef unsigned long long u64;
typedef unsigned short u16;
typedef unsigned int u32;

// ---------------------------------------------------------------------------
// HierarchicalLFQHVQVAE forward — R4.
// - Stage-1 dist: bf16 MFMA with A=codebook / B=batch (batch rows on 4 lanes),
//   u32 keys (20-bit quantized dist | 12-bit code), best-2 per 128-code block.
//   Epilogue: per-thread serial insert + 2 shuffles + 2-way LDS merge.
// - Stage-2: top-8 of u32 candidates, exact f32 re-rank, gather+commit+idx.
// - Projections (enc1, enc2, z-proj, q-proj): split-bf16 3-term MFMA.
// - Decoder: plain bf16 MFMA.
// ---------------------------------------------------------------------------

namespace {

constexpr int kBatch = 32768;

__device__ __forceinline__ float gelu_f(float x) {
  return 0.5f * x * (1.0f + erff(x * 0.70710678118654752440f));
}
__device__ __forceinline__ float sigmoid_f(float x) {
  return 1.0f / (1.0f + expf(-x));
}
__device__ __forceinline__ u64 pack_key(float d, unsigned j) {
  unsigned u = __float_as_uint(d);
  u = (u & 0x80000000u) ? ~u : (u | 0x80000000u);
  return ((u64)u << 32) | j;
}
__device__ __forceinline__ u16 bf16_rne(float x) {
  unsigned u = __float_as_uint(x);
  unsigned r = (u + 0x7FFFu + ((u >> 16) & 1u)) >> 16;
  return (u16)r;
}
__device__ __forceinline__ float bf16_to_f(u16 h) {
  return __uint_as_float((unsigned)h << 16);
}
__device__ __forceinline__ u64 min64(u64 a, u64 b) { return a < b ? a : b; }

__device__ __forceinline__ void load_lds16(const void* g, void* l) {
  __builtin_amdgcn_global_load_lds(
      (const __attribute__((address_space(1))) void*)g,
      (__attribute__((address_space(3))) void*)l, 16, 0, 0);
}

typedef short bf16x8 __attribute__((ext_vector_type(8)));
typedef float f32x4 __attribute__((ext_vector_type(4)));

// ===========================================================================
// Prep kernels
// ===========================================================================
__global__ void cb_norm_kernel(const float* __restrict__ cb,
                               float* __restrict__ cbn, int K) {
  const int row = blockIdx.x * 4 + (threadIdx.x >> 6);
  const int lane = threadIdx.x & 63;
  double s = 0.0;
  for (int k = lane; k < K; k += 64) {
    const float v = cb[(size_t)row * K + k];
    s += (double)v * (double)v;
  }
#pragma unroll
  for (int o = 32; o > 0; o >>= 1) s += __shfl_down(s, o);
  if (lane == 0) cbn[row] = (float)s;
}

__global__ void cast_all_kernel(const float* zcb, u16* zcbh, const float* qcb,
                                u16* qcbh, const float* dW1, u16* dW1b,
                                const float* dW2, u16* dW2b, const float* oW,
                                u16* oWb) {
  const int stride = gridDim.x * 256;
  const int t0 = blockIdx.x * 256 + threadIdx.x;
  for (int i = t0; i < 4096 * 256; i += stride) zcbh[i] = bf16_rne(zcb[i]);
  for (int i = t0; i < 2048 * 128; i += stride) qcbh[i] = bf16_rne(qcb[i]);
  for (int i = t0; i < 64 * 128; i += stride) dW1b[i] = bf16_rne(dW1[i]);
  for (int i = t0; i < 512 * 64; i += stride) dW2b[i] = bf16_rne(dW2[i]);
  for (int i = t0; i < 512 * 512; i += stride) oWb[i] = bf16_rne(oW[i]);
}

// Lipschitz row norm + split to [wh(K) | wl(K)]
__global__ void norm_split_kernel(const float* __restrict__ W,
                                  const float* __restrict__ ci,
                                  u16* __restrict__ D, int K) {
  const int row = blockIdx.x;
  const int tid = threadIdx.x;
  float s = 0.f;
  for (int k = tid; k < K; k += 256) s += fabsf(W[(size_t)row * K + k]);
#pragma unroll
  for (int o = 32; o > 0; o >>= 1) s += __shfl_down(s, o);
  __shared__ float p[4];
  if ((tid & 63) == 0) p[tid >> 6] = s;
  __syncthreads();
  const float tot = p[0] + p[1] + p[2] + p[3];
  const float c = ci[row];
  const float sp = (c > 20.f) ? c : log1pf(expf(c));
  const float scale = fminf(1.f, sp / tot);
  for (int k = tid; k < K; k += 256) {
    const float v = W[(size_t)row * K + k] * scale;
    const u16 h = bf16_rne(v);
    const u16 l = bf16_rne(v - bf16_to_f(h));
    D[(size_t)row * 2 * K + k] = h;
    D[(size_t)row * 2 * K + K + k] = l;
  }
}

__global__ void split2_kernel(const float* __restrict__ W, u16* __restrict__ D,
                              int kshift, int total) {
  const int i = blockIdx.x * 256 + threadIdx.x;
  if (i >= total) return;
  const int K = 1 << kshift;
  const int r = i >> kshift, k = i & (K - 1);
  const float v = W[i];
  const u16 h = bf16_rne(v);
  const u16 l = bf16_rne(v - bf16_to_f(h));
  D[(size_t)r * 2 * K + k] = h;
  D[(size_t)r * 2 * K + K + k] = l;
}

// ===========================================================================
// Plain bf16 MFMA GEMM (decoder). Modes: GELU->bf16 | RECON (f32 + MSE).
// ===========================================================================
enum { M_GELU_B16 = 0, M_RECON = 1 };

template <int TM, int TN, int MODE>
__global__ __launch_bounds__(256) void gemm_bf16(
    const u16* __restrict__ A, const u16* __restrict__ B,
    const float* __restrict__ bias, void* __restrict__ Cv,
    const float* __restrict__ X, float* __restrict__ sumptr, int Ktot, int N) {
  __shared__ __align__(16) u16 As[TM * 64];
  __shared__ __align__(16) u16 Bs[TN * 64];
  constexpr int AIT = (TM * 8) / 256;
  constexpr int BIT = (TN * 8) / 256;
  const int tid = threadIdx.x;
  const int lane = tid & 63, w = tid >> 6;
  const int quad = lane >> 4, l15 = lane & 15;
  const int waveM = (TN == 128) ? (w & 1) * 64 : w * 64;
  const int waveN = (TN == 128) ? (w >> 1) * 64 : 0;
  const int rowBase = blockIdx.y * TM;
  const int colBase = blockIdx.x * TN;

  f32x4 acc[4][4] = {};

  for (int k0 = 0; k0 < Ktot; k0 += 64) {
    __syncthreads();
#pragma unroll
    for (int i = 0; i < AIT; ++i) {
      const int ch = i * 256 + tid;
      const int r = ch >> 3, c = ch & 7, g = c ^ (r & 7);
      load_lds16(A + (size_t)(rowBase + r) * Ktot + k0 + g * 8,
                 (char*)As + ch * 16);
    }
#pragma unroll
    for (int i = 0; i < BIT; ++i) {
      const int ch = i * 256 + tid;
      const int r = ch >> 3, c = ch & 7, g = c ^ (r & 7);
      load_lds16(B + (size_t)(colBase + r) * Ktot + k0 + g * 8,
                 (char*)Bs + ch * 16);
    }
    __syncthreads();
#pragma unroll
    for (int ks = 0; ks < 2; ++ks) {
      bf16x8 af[4], bf[4];
      const int ch = ks * 4 + quad;
#pragma unroll
      for (int mi = 0; mi < 4; ++mi) {
        const int rl = waveM + mi * 16 + l15;
        af[mi] = *(const bf16x8*)(As + rl * 64 + (ch ^ (rl & 7)) * 8);
      }
#pragma unroll
      for (int ni = 0; ni < 4; ++ni) {
        const int rl = waveN + ni * 16 + l15;
        bf[ni] = *(const bf16x8*)(Bs + rl * 64 + (ch ^ (rl & 7)) * 8);
      }
#pragma unroll
      for (int mi = 0; mi < 4; ++mi)
#pragma unroll
        for (int ni = 0; ni < 4; ++ni)
          acc[mi][ni] = __builtin_amdgcn_mfma_f32_16x16x32_bf16(
              af[mi], bf[ni], acc[mi][ni], 0, 0, 0);
    }
  }

  if constexpr (MODE == M_GELU_B16) {
    u16* C = (u16*)Cv;
#pragma unroll
    for (int mi = 0; mi < 4; ++mi)
#pragma unroll
      for (int r = 0; r < 4; ++r) {
        const int row = rowBase + waveM + mi * 16 + quad * 4 + r;
#pragma unroll
        for (int ni = 0; ni < 4; ++ni) {
          const int col = colBase + waveN + ni * 16 + l15;
          C[(size_t)row * N + col] =
              bf16_rne(gelu_f(acc[mi][ni][r] + bias[col]));
        }
      }
  } else {  // M_RECON
    float* C = (float*)Cv;
    float local = 0.f;
#pragma unroll
    for (int mi = 0; mi < 4; ++mi)
#pragma unroll
      for (int r = 0; r < 4; ++r) {
        const int row = rowBase + waveM + mi * 16 + quad * 4 + r;
#pragma unroll
        for (int ni = 0; ni < 4; ++ni) {
          const int col = colBase + waveN + ni * 16 + l15;
          const float val = acc[mi][ni][r] + bias[col];
          const float d = val - X[(size_t)row * N + col];
          local += d * d;
          C[(size_t)row * N + col] = val;
        }
      }
#pragma unroll
    for (int o = 32; o > 0; o >>= 1) local += __shfl_down(local, o);
    __shared__ float psum[4];
    if (lane == 0) psum[w] = local;
    __syncthreads();
    if (tid == 0) atomicAdd(sumptr, psum[0] + psum[1] + psum[2] + psum[3]);
  }
}

// ===========================================================================
// Stage-1 distance: A=codebook bf16 [N][K], B=batch bf16 [M][K].
// 128 codes x 128 batch-rows per block. acc row m = code, col n = batch.
// Key: u32 = (clamp((dist+256)*512) << 12) | code. Best-2 per block ->
// cand[batchRow][2*nx], one 8B store per (row, block).
// ===========================================================================
__global__ __launch_bounds__(256) void dist2_kernel(
    const u16* __restrict__ CB, const u16* __restrict__ ZB,
    const float* __restrict__ cbn, u32* __restrict__ cand, int Ktot, int nx) {
  __shared__ __align__(16) u16 As[128 * 64];
  __shared__ __align__(16) u16 Bs[128 * 64];
  __shared__ u32 wred[128][2][2];
  const int tid = threadIdx.x;
  const int lane = tid & 63, w = tid >> 6;
  const int quad = lane >> 4, l15 = lane & 15;
  const int waveM = (w & 1) * 64, waveN = (w >> 1) * 64;
  const int codeBase = blockIdx.x * 128;
  const int rowBase = blockIdx.y * 128;

  f32x4 acc[4][4] = {};

  for (int k0 = 0; k0 < Ktot; k0 += 64) {
    __syncthreads();
#pragma unroll
    for (int i = 0; i < 4; ++i) {
      const int ch = i * 256 + tid;
      const int r = ch >> 3, c = ch & 7, g = c ^ (r & 7);
      load_lds16(CB + (size_t)(codeBase + r) * Ktot + k0 + g * 8,
                 (char*)As + ch * 16);
      load_lds16(ZB + (size_t)(rowBase + r) * Ktot + k0 + g * 8,
                 (char*)Bs + ch * 16);
    }
    __syncthreads();
#pragma unroll
    for (int ks = 0; ks < 2; ++ks) {
      bf16x8 af[4], bf[4];
      const int ch = ks * 4 + quad;
#pragma unroll
      for (int mi = 0; mi < 4; ++mi) {
        const int rl = waveM + mi * 16 + l15;
        af[mi] = *(const bf16x8*)(As + rl * 64 + (ch ^ (rl & 7)) * 8);
      }
#pragma unroll
      for (int ni = 0; ni < 4; ++ni) {
        const int rl = waveN + ni * 16 + l15;
        bf[ni] = *(const bf16x8*)(Bs + rl * 64 + (ch ^ (rl & 7)) * 8);
      }
#pragma unroll
      for (int mi = 0; mi < 4; ++mi)
#pragma unroll
        for (int ni = 0; ni < 4; ++ni)
          acc[mi][ni] = __builtin_amdgcn_mfma_f32_16x16x32_bf16(
              af[mi], bf[ni], acc[mi][ni], 0, 0, 0);
    }
  }

  // pre-scale: keyf = (cbn[code] + 256)*512 - 1024*acc ; iv=trunc, clamp 2^20
  float cnf[4][4];
  unsigned codeLoc[4][4];
#pragma unroll
  for (int mi = 0; mi < 4; ++mi)
#pragma unroll
    for (int r = 0; r < 4; ++r) {
      const unsigned code = codeBase + waveM + mi * 16 + quad * 4 + r;
      codeLoc[mi][r] = code;
      cnf[mi][r] = cbn[code] * 512.0f + 131072.0f;
    }
#pragma unroll
  for (int ni = 0; ni < 4; ++ni) {
    u32 b0 = ~0u, b1 = ~0u;
#pragma unroll
    for (int mi = 0; mi < 4; ++mi)
#pragma unroll
      for (int r = 0; r < 4; ++r) {
        const float kf = fmaf(acc[mi][ni][r], -1024.0f, cnf[mi][r]);
        u32 iv = (u32)kf;                       // saturating cvt
        iv = iv > 0xFFFFFu ? 0xFFFFFu : iv;
        const u32 key = (iv << 12) | codeLoc[mi][r];
        if (key < b0) { b1 = b0; b0 = key; }
        else if (key < b1) { b1 = key; }
      }
    // lanes {l15, l15+16, l15+32, l15+48} hold the same batch row
#pragma unroll
    for (int off = 16; off < 64; off <<= 1) {
      const u32 o0 = __shfl_xor(b0, off);
      const u32 o1 = __shfl_xor(b1, off);
      const u32 n0 = min(b0, o0);
      const u32 n1 = min(max(b0, o0), min(b1, o1));
      b0 = n0; b1 = n1;
    }
    if (quad == 0) {
      wred[waveN + ni * 16 + l15][w & 1][0] = b0;
      wred[waveN + ni * 16 + l15][w & 1][1] = b1;
    }
  }
  __syncthreads();
  if (tid < 128) {
    const u32 a0 = wred[tid][0][0], a1 = wred[tid][0][1];
    const u32 c0 = wred[tid][1][0], c1 = wred[tid][1][1];
    const u32 b0 = min(a0, c0);
    const u32 b1 = min(max(a0, c0), min(a1, c1));
    u32* dst = cand + (size_t)(rowBase + tid) * (2 * nx) + 2 * blockIdx.x;
    *(u64*)dst = ((u64)b1 << 32) | b0;
  }
}

// ===========================================================================
// Split-f32 MFMA GEMM: A f32 split in-kernel; B pre-split [N][2K] = [wh|wl].
// acc += ah.bh + al.bh + ah.bl. Modes: GELU->f32 | SIGMOID->f32+bf16 aux.
// ===========================================================================
enum { S_GELU_F32 = 0, S_SIG_ZE = 1 };

template <int TM, int TN, int MODE>
__global__ __launch_bounds__(256) void gemm_sf32(
    const float* __restrict__ A, const u16* __restrict__ B2,
    const float* __restrict__ bias, float* __restrict__ C,
    u16* __restrict__ Caux, int K, int N) {
  __shared__ __align__(16) u16 Ah[TM * 64];
  __shared__ __align__(16) u16 Al[TM * 64];
  __shared__ __align__(16) u16 Bh[TN * 64];
  __shared__ __align__(16) u16 Bl[TN * 64];
  const int tid = threadIdx.x;
  const int lane = tid & 63, w = tid >> 6;
  const int quad = lane >> 4, l15 = lane & 15;
  const int waveM = (TN == 128) ? (w & 1) * 64 : w * 64;
  const int waveN = (TN == 128) ? (w >> 1) * 64 : 0;
  const int rowBase = blockIdx.y * TM;
  const int colBase = blockIdx.x * TN;

  f32x4 acc[4][4] = {};

  for (int k0 = 0; k0 < K; k0 += 64) {
    __syncthreads();
#pragma unroll
    for (int i = 0; i < TN / 32; ++i) {
      const int ch = i * 256 + tid;
      const int r = ch >> 3, c = ch & 7, g = c ^ (r & 7);
      const size_t rb = (size_t)(colBase + r) * 2 * K + k0 + g * 8;
      load_lds16(B2 + rb, (char*)Bh + ch * 16);
      load_lds16(B2 + rb + K, (char*)Bl + ch * 16);
    }
#pragma unroll
    for (int i = 0; i < TM / 16; ++i) {
      const int ch = i * 256 + tid;  // TM rows x 16 float4-chunks
      const int r = ch >> 4, c4 = ch & 15;
      const float4 v =
          *(const float4*)(A + (size_t)(rowBase + r) * K + k0 + c4 * 4);
      u16 hv[4], lv[4];
      const float vv[4] = {v.x, v.y, v.z, v.w};
#pragma unroll
      for (int j = 0; j < 4; ++j) {
        hv[j] = bf16_rne(vv[j]);
        lv[j] = bf16_rne(vv[j] - bf16_to_f(hv[j]));
      }
      const int g = (c4 >> 1) ^ (r & 7);
      const int off = r * 64 + g * 8 + (c4 & 1) * 4;
      *(ushort4*)(Ah + off) = make_ushort4(hv[0], hv[1], hv[2], hv[3]);
      *(ushort4*)(Al + off) = make_ushort4(lv[0], lv[1], lv[2], lv[3]);
    }
    __syncthreads();
#pragma unroll
    for (int ks = 0; ks < 2; ++ks) {
      bf16x8 ahf[4], alf[4], bhf[4], blf[4];
      const int ch = ks * 4 + quad;
#pragma unroll
      for (int mi = 0; mi < 4; ++mi) {
        const int rl = waveM + mi * 16 + l15;
        const int so = rl * 64 + (ch ^ (rl & 7)) * 8;
        ahf[mi] = *(const bf16x8*)(Ah + so);
        alf[mi] = *(const bf16x8*)(Al + so);
      }
#pragma unroll
      for (int ni = 0; ni < 4; ++ni) {
        const int rl = waveN + ni * 16 + l15;
        const int so = rl * 64 + (ch ^ (rl & 7)) * 8;
        bhf[ni] = *(const bf16x8*)(Bh + so);
        blf[ni] = *(const bf16x8*)(Bl + so);
      }
#pragma unroll
      for (int mi = 0; mi < 4; ++mi)
#pragma unroll
        for (int ni = 0; ni < 4; ++ni) {
          acc[mi][ni] = __builtin_amdgcn_mfma_f32_16x16x32_bf16(
              ahf[mi], bhf[ni], acc[mi][ni], 0, 0, 0);
          acc[mi][ni] = __builtin_amdgcn_mfma_f32_16x16x32_bf16(
              alf[mi], bhf[ni], acc[mi][ni], 0, 0, 0);
          acc[mi][ni] = __builtin_amdgcn_mfma_f32_16x16x32_bf16(
              ahf[mi], blf[ni], acc[mi][ni], 0, 0, 0);
        }
    }
  }

#pragma unroll
  for (int mi = 0; mi < 4; ++mi)
#pragma unroll
    for (int r = 0; r < 4; ++r) {
      const int row = rowBase + waveM + mi * 16 + quad * 4 + r;
#pragma unroll
      for (int ni = 0; ni < 4; ++ni) {
        const int col = colBase + waveN + ni * 16 + l15;
        const float pre = acc[mi][ni][r] + bias[col];
        if constexpr (MODE == S_GELU_F32) {
          C[(size_t)row * N + col] = gelu_f(pre);
        } else {
          const float s = sigmoid_f(pre);
          C[(size_t)row * N + col] = s;
          Caux[(size_t)row * N + col] = bf16_rne(s);
        }
      }
    }
}

// ===========================================================================
// Stage-2: top-8 of NC u32 candidates -> exact f32 re-rank -> gather +
// commit MSE + idx. LEVEL 0 writes z_q f32 ws; LEVEL 1 writes q_q bf16.
// ===========================================================================
template <int K, int NC, int LEVEL>
__global__ __launch_bounds__(256) void rerank_kernel(
    const u32* __restrict__ cand, const float* __restrict__ ze,
    const float* __restrict__ cb, const float* __restrict__ cbn,
    float* __restrict__ outq, float* __restrict__ wsq,
    u16* __restrict__ wsqb, float* __restrict__ out_idx,
    float* __restrict__ sumptr) {
  const int w = threadIdx.x >> 6, lane = threadIdx.x & 63;
  const int row = blockIdx.x * 4 + w;

  u32 key = (lane < NC) ? cand[(size_t)row * NC + lane] : ~0u;
  unsigned topcode[8];
#pragma unroll
  for (int t = 0; t < 8; ++t) {
    u32 m = key;
#pragma unroll
    for (int off = 1; off < 64; off <<= 1) m = min(m, __shfl_xor(m, off));
    topcode[t] = m & 0xFFFu;
    if (key == m) key = ~0u;
  }

  const int g = lane >> 3, sub = lane & 7;
  unsigned ci = topcode[0];
#pragma unroll
  for (int t = 1; t < 8; ++t) ci = (g == t) ? topcode[t] : ci;

  const float* zr = ze + (size_t)row * K;
  const float* cr = cb + (size_t)ci * K;
  float dot = 0.f;
#pragma unroll
  for (int k = sub * (K / 8); k < (sub + 1) * (K / 8); k += 4) {
    const float4 zv = *(const float4*)(zr + k);
    const float4 cv = *(const float4*)(cr + k);
    dot = fmaf(zv.x, cv.x, dot);
    dot = fmaf(zv.y, cv.y, dot);
    dot = fmaf(zv.z, cv.z, dot);
    dot = fmaf(zv.w, cv.w, dot);
  }
#pragma unroll
  for (int off = 1; off < 8; off <<= 1) dot += __shfl_xor(dot, off);
  u64 k2 = pack_key(cbn[ci] - 2.0f * dot, ci);
#pragma unroll
  for (int off = 8; off < 64; off <<= 1) k2 = min64(k2, __shfl_xor(k2, off));
  const unsigned best = (unsigned)k2;
  if (lane == 0) out_idx[row] = (float)best;

  const float* br = cb + (size_t)best * K;
  float local = 0.f;
  for (int c = lane; c < K; c += 64) {
    const float v = br[c];
    const float z = zr[c];
    const float d = z - v;
    local += d * d;
    outq[(size_t)row * K + c] = v;
    if (LEVEL == 0) wsq[(size_t)row * K + c] = v;
    else wsqb[(size_t)row * K + c] = bf16_rne(v);
  }
#pragma unroll
  for (int o = 32; o > 0; o >>= 1) local += __shfl_down(local, o);
  __shared__ float p[4];
  if (lane == 0) p[w] = local;
  __syncthreads();
  if (threadIdx.x == 0) atomicAdd(sumptr, p[0] + p[1] + p[2] + p[3]);
}

__global__ void finalize_kernel(const float* __restrict__ sums,
                                float* __restrict__ out) {
  const float cz = sums[0] / ((float)kBatch * 256.f);
  const float cq = sums[1] / ((float)kBatch * 128.f);
  const float rec = sums[2] / ((float)kBatch * 512.f);
  out[0] = rec + 0.5f * cz + 0.5f * cq;
  out[1] = rec;
  out[2] = cz;
  out[3] = cz;
  out[4] = cq;
  out[5] = cq;
}

}  // namespace

extern "C" void kernel_launch(void* const* d_in, const int* in_sizes, int n_in,
                              void* d_out, int out_size, void* d_ws,
                              size_t ws_size, hipStream_t stream) {
  const float* x   = (const float*)d_in[0];
  const float* eW1 = (const float*)d_in[1];
  const float* eb1 = (const float*)d_in[2];
  const float* eW2 = (const float*)d_in[3];
  const float* eb2 = (const float*)d_in[4];
  const float* zW  = (const float*)d_in[5];
  const float* zb  = (const float*)d_in[6];
  const float* zci = (const float*)d_in[7];
  const float* zcb = (const float*)d_in[8];
  const float* qW  = (const float*)d_in[9];
  const float* qb  = (const float*)d_in[10];
  const float* qci = (const float*)d_in[11];
  const float* qcb = (const float*)d_in[12];
  const float* dW1 = (const float*)d_in[13];
  const float* db1 = (const float*)d_in[14];
  const float* dW2 = (const float*)d_in[15];
  const float* db2 = (const float*)d_in[16];
  const float* oW  = (const float*)d_in[17];
  const float* ob  = (const float*)d_in[18];

  float* out = (float*)d_out;
  float* out_xr = out + 6;
  float* out_zq = out_xr + (size_t)32768 * 512;
  float* out_qq = out_zq + (size_t)32768 * 256;
  float* out_zi = out_qq + (size_t)32768 * 128;
  float* out_qi = out_zi + 32768;

  // ---- workspace layout (high-water 0x7C00000 = 124 MiB) -----------------
  char* wsb = (char*)d_ws;
  u16*  zWns = (u16*) (wsb + 0x0000000);  // 256x1024  512K
  u16*  qWns = (u16*) (wsb + 0x0080000);  // 128x512   128K
  u16*  eW2s = (u16*) (wsb + 0x00A0000);  // 512x128   128K
  u16*  dW1b = (u16*) (wsb + 0x00C0000);  // 64x128     16K
  u16*  dW2b = (u16*) (wsb + 0x00C4000);  // 512x64     64K
  u16*  oWb  = (u16*) (wsb + 0x00D4000);  // 512x512   512K
  u16*  zcbh = (u16*) (wsb + 0x0154000);  // 4096x256    2M
  u16*  qcbh = (u16*) (wsb + 0x0354000);  // 2048x128  512K
  float* zcbn = (float*)(wsb + 0x03D4000); // 16K
  float* qcbn = (float*)(wsb + 0x03D8000); // 8K
  float* sums = (float*)(wsb + 0x03DA000); // 3 floats
  u16*  eW1s = (u16*) (wsb + 0x03DC000);   // 64x1024   128K
  // time-windowed regions:
  float* h1   = (float*)(wsb + 0x0400000); // 8M  [enc1->enc2]
  u32*  candq = (u32*)  (wsb + 0x0400000); //   4M  [q-dist1 -> q-rerank]
  u16*  h1b   = (u16*)  (wsb + 0x0400000); //   4M  [dec1 -> dec2]
  float* ze   = (float*)(wsb + 0x0C00000); // 32M [z-proj -> z-rerank]
  u16*  hb    = (u16*)  (wsb + 0x0C00000); //   32M [dec2 -> recon]
  u16*  zeb   = (u16*)  (wsb + 0x2C00000); // 16M [z-proj -> z-dist1]
  float* qe   = (float*)(wsb + 0x2C00000); //   16M [q-proj -> q-rerank]
  float* h    = (float*)(wsb + 0x3C00000); // 64M [enc2 -> z-proj]
  u32*  candz = (u32*)  (wsb + 0x3C00000); //   8M  [z-dist1 -> z-rerank]
  float* zqws = (float*)(wsb + 0x4C00000); //   32M [z-rerank -> q-proj]
  u16*  qeb   = (u16*)  (wsb + 0x6C00000); //   8M  [q-proj -> q-dist1]
  u16*  qqb   = (u16*)  (wsb + 0x7400000); //   8M  [q-rerank -> dec1]

  hipMemsetAsync(sums, 0, 3 * sizeof(float), stream);

  // ---- prep ----
  cb_norm_kernel<<<1024, 256, 0, stream>>>(zcb, zcbn, 256);
  cb_norm_kernel<<<512, 256, 0, stream>>>(qcb, qcbn, 128);
  cast_all_kernel<<<512, 256, 0, stream>>>(zcb, zcbh, qcb, qcbh, dW1, dW1b,
                                           dW2, dW2b, oW, oWb);
  norm_split_kernel<<<256, 256, 0, stream>>>(zW, zci, zWns, 512);
  norm_split_kernel<<<128, 256, 0, stream>>>(qW, qci, qWns, 256);
  split2_kernel<<<128, 256, 0, stream>>>(eW2, eW2s, 6, 512 * 64);
  split2_kernel<<<128, 256, 0, stream>>>(eW1, eW1s, 9, 64 * 512);

  // ---- encoder ----
  gemm_sf32<256, 64, S_GELU_F32><<<dim3(1, 128), 256, 0, stream>>>(
      x, eW1s, eb1, h1, nullptr, 512, 64);
  gemm_sf32<128, 128, S_GELU_F32><<<dim3(4, 256), 256, 0, stream>>>(
      h1, eW2s, eb2, h, nullptr, 64, 512);
  gemm_sf32<128, 128, S_SIG_ZE><<<dim3(2, 256), 256, 0, stream>>>(
      h, zWns, zb, ze, zeb, 512, 256);

  // ---- z quantize ----
  dist2_kernel<<<dim3(32, 256), 256, 0, stream>>>(zcbh, zeb, zcbn, candz,
                                                  256, 32);
  rerank_kernel<256, 64, 0><<<8192, 256, 0, stream>>>(
      candz, ze, zcb, zcbn, out_zq, zqws, nullptr, out_zi, &sums[0]);

  // ---- q level ----
  gemm_sf32<128, 128, S_SIG_ZE><<<dim3(1, 256), 256, 0, stream>>>(
      zqws, qWns, qb, qe, qeb, 256, 128);
  dist2_kernel<<<dim3(16, 256), 256, 0, stream>>>(qcbh, qeb, qcbn, candq,
                                                  128, 16);
  rerank_kernel<128, 32, 1><<<8192, 256, 0, stream>>>(
      candq, qe, qcb, qcbn, out_qq, nullptr, qqb, out_qi, &sums[1]);

  // ---- decoder ----
  gemm_bf16<256, 64, M_GELU_B16><<<dim3(1, 128), 256, 0, stream>>>(
      qqb, dW1b, db1, h1b, nullptr, nullptr, 128, 64);
  gemm_bf16<128, 128, M_GELU_B16><<<dim3(4, 256), 256, 0, stream>>>(
      h1b, dW2b, db2, hb, nullptr, nullptr, 64, 512);
  gemm_bf16<128, 128, M_RECON><<<dim3(4, 256), 256, 0, stream>>>(
      hb, oWb, ob, out_xr, x, &sums[2], 512, 512);

  finalize_kernel<<<1, 1, 0, stream>>>(sums, out);

  (void)in_sizes; (void)n_in; (void)out_size; (void)ws_size;
}